// Round 7
// baseline (2803.389 us; speedup 1.0000x reference)
//
#include <hip/hip_runtime.h>
#include <math.h>

// N=100000 nodes, E=1600000 edges, HID=64, C=2, fp32.
// Hard-won constraints (R2-R6):
//  * Weights staged in LDS before unrolled gemm cores (global-weight unrolled
//    loads -> VGPR hoist -> spill; R2/R3 WRITE 1-3GB).
//  * option-A epi demand ~232 VGPR; option-C (4x4) demand >256 -> spills (R6).
//  * __launch_bounds__(512) DEFAULTS the cap to 128 -> spill (R5). 232 fits
//    2 waves/EU, so 512-thread blocks need explicit __launch_bounds__(512,2)
//    (cap 256). This gives 8 waves/CU on the 138KB-LDS epi block.
// R7: k_epi = R5 structure + (512,2); k_gather = 8 groups x 8 lanes (fewer
// serial swizzles, 2x load ILP); k_rn fused into k_mlp output phase.

__device__ __forceinline__ void fma4(float (&acc)[4], float a, const float4& w) {
    acc[0] = fmaf(a, w.x, acc[0]);
    acc[1] = fmaf(a, w.y, acc[1]);
    acc[2] = fmaf(a, w.z, acc[2]);
    acc[3] = fmaf(a, w.w, acc[3]);
}

// 256 threads: stage 32 rows x 64 cols (8 floats/thread)
__device__ __forceinline__ void load_rows32(const float* __restrict__ src, int row0, int n,
                                            float (*dst)[68], int t)
{
    int e = t * 8;
    int r = e >> 6, i = e & 63;
    int grow = row0 + r;
    float4 v0 = make_float4(0.f, 0.f, 0.f, 0.f), v1 = v0;
    if (grow < n) {
        const float* p = src + (size_t)grow * 64 + i;
        v0 = *(const float4*)p;
        v1 = *(const float4*)(p + 4);
    }
    *(float4*)&dst[r][i]     = v0;
    *(float4*)&dst[r][i + 4] = v1;
}

// 512 threads: stage 64 rows x 64 cols (8 floats/thread)
__device__ __forceinline__ void load_rows64_512(const float* __restrict__ src, int row0, int n,
                                                float (*dst)[68], int t)
{
    int r = t >> 3, i = (t & 7) * 8;
    int grow = row0 + r;
    float4 v0 = make_float4(0.f, 0.f, 0.f, 0.f), v1 = v0;
    if (grow < n) {
        const float* p = src + (size_t)grow * 64 + i;
        v0 = *(const float4*)p;
        v1 = *(const float4*)(p + 4);
    }
    *(float4*)&dst[r][i]     = v0;
    *(float4*)&dst[r][i + 4] = v1;
}

// ---- option A core: 2 rows x 4 cols ----
__device__ __forceinline__ void gemm_core(const float (*in)[68], const float* w,
                                          const float* b, int rg, int cg,
                                          float (&acc0)[4], float (&acc1)[4])
{
#pragma unroll
    for (int dc = 0; dc < 4; dc++) { float bb = b[4*cg + dc]; acc0[dc] = bb; acc1[dc] = bb; }
    const int r0 = 2 * rg, r1 = 2 * rg + 1;
#pragma unroll
    for (int i = 0; i < 64; i += 4) {
        float4 a0 = *(const float4*)&in[r0][i];
        float4 a1 = *(const float4*)&in[r1][i];
        float4 q0 = *(const float4*)&w[(i + 0) * 64 + 4 * cg];
        float4 q1 = *(const float4*)&w[(i + 1) * 64 + 4 * cg];
        float4 q2 = *(const float4*)&w[(i + 2) * 64 + 4 * cg];
        float4 q3 = *(const float4*)&w[(i + 3) * 64 + 4 * cg];
        fma4(acc0, a0.x, q0); fma4(acc0, a0.y, q1); fma4(acc0, a0.z, q2); fma4(acc0, a0.w, q3);
        fma4(acc1, a1.x, q0); fma4(acc1, a1.y, q1); fma4(acc1, a1.z, q2); fma4(acc1, a1.w, q3);
    }
}

template <int MODE>  // 0=none, 1=relu, 2=tanh
__device__ __forceinline__ void gemm_lds(const float (*in)[68], const float* w,
                                         const float* b, float (*out)[68],
                                         int rg, int cg)
{
    float a0[4], a1[4];
    gemm_core(in, w, b, rg, cg, a0, a1);
#pragma unroll
    for (int dc = 0; dc < 4; dc++) {
        float v0 = a0[dc], v1 = a1[dc];
        if (MODE == 1) { v0 = fmaxf(v0, 0.f); v1 = fmaxf(v1, 0.f); }
        if (MODE == 2) { v0 = tanhf(v0); v1 = tanhf(v1); }
        a0[dc] = v0; a1[dc] = v1;
    }
    *(float4*)&out[2 * rg][4 * cg]     = make_float4(a0[0], a0[1], a0[2], a0[3]);
    *(float4*)&out[2 * rg + 1][4 * cg] = make_float4(a1[0], a1[1], a1[2], a1[3]);
}

// ---------------- CSR build (single arr[n+1]) ----------------

__global__ __launch_bounds__(256) void k_zero(int* __restrict__ arr, int n1)
{
    int i = blockIdx.x * 256 + threadIdx.x;
    if (i < n1) arr[i] = 0;
}

__global__ __launch_bounds__(256) void k_count(const int* __restrict__ col, int* __restrict__ arr, int e)
{
    int i = blockIdx.x * 256 + threadIdx.x;
    if (i < e) atomicAdd(&arr[col[i]], 1);
}

__global__ __launch_bounds__(1024) void k_scan(int* __restrict__ arr, int n)
{
    __shared__ int s[1024];
    int t = threadIdx.x;
    int chunk = (n + 1023) / 1024;
    int start = t * chunk;
    int end = min(n, start + chunk);
    int tot = 0;
    for (int i = start; i < end; i++) tot += arr[i];
    s[t] = tot;
    __syncthreads();
    for (int d = 1; d < 1024; d <<= 1) {
        int v = (t >= d) ? s[t - d] : 0;
        __syncthreads();
        s[t] += v;
        __syncthreads();
    }
    int run = s[t] - tot;
    for (int i = start; i < end; i++) { int v = arr[i]; arr[i] = run; run += v; }
    if (t == 1023) arr[n] = s[1023];
}

// after fill: arr[c] = end of segment c ; start(c) = c ? arr[c-1] : 0
__global__ __launch_bounds__(256) void k_fill(const int* __restrict__ row, const int* __restrict__ col,
                                              int* __restrict__ arr, int* __restrict__ csr, int e)
{
    int i = blockIdx.x * 256 + threadIdx.x;
    if (i < e) {
        int c = col[i];
        int p = atomicAdd(&arr[c], 1);
        csr[p] = row[i];
    }
}

// ---------------- node MLP + fused per-node scalars ----------------
// 256 thr, 32-row tiles, option A. After the w3 layer each thread holds its
// (2 rows x 4 cols) of h: reduce sumsq over the 16 cg lanes -> nrm2.

__global__ __launch_bounds__(256) void k_mlp(const float* __restrict__ x,
    const float* __restrict__ w1, const float* __restrict__ b1,
    const float* __restrict__ w2, const float* __restrict__ b2,
    const float* __restrict__ w3, const float* __restrict__ b3,
    const int* __restrict__ arr, float* __restrict__ h,
    float2* __restrict__ nrm2, int n)
{
    __shared__ float w1s[4096], w2s[4096], w3s[4096];
    __shared__ float b1s[64], b2s[64], b3s[64];
    __shared__ float xs[32][68], hs[32][68];
    int t = threadIdx.x;
    for (int i = t; i < 4096; i += 256) { w1s[i] = w1[i]; w2s[i] = w2[i]; w3s[i] = w3[i]; }
    if (t < 64) { b1s[t] = b1[t]; b2s[t] = b2[t]; b3s[t] = b3[t]; }
    __syncthreads();
    int cg = t & 15, rg = t >> 4;
    for (int row0 = blockIdx.x * 32; row0 < n; row0 += gridDim.x * 32) {
        load_rows32(x, row0, n, xs, t);
        __syncthreads();
        gemm_lds<1>(xs, w1s, b1s, hs, rg, cg);
        __syncthreads();
        gemm_lds<1>(hs, w2s, b2s, xs, rg, cg);
        __syncthreads();
        {
            float a0[4], a1[4];
            gemm_core(xs, w3s, b3s, rg, cg, a0, a1);
            int r0 = row0 + 2 * rg, r1 = r0 + 1;
            if (r0 < n) *(float4*)&h[(size_t)r0 * 64 + 4 * cg] = make_float4(a0[0], a0[1], a0[2], a0[3]);
            if (r1 < n) *(float4*)&h[(size_t)r1 * 64 + 4 * cg] = make_float4(a1[0], a1[1], a1[2], a1[3]);
            float s0 = a0[0]*a0[0] + a0[1]*a0[1] + a0[2]*a0[2] + a0[3]*a0[3];
            float s1 = a1[0]*a1[0] + a1[1]*a1[1] + a1[2]*a1[2] + a1[3]*a1[3];
#pragma unroll
            for (int d = 1; d < 16; d <<= 1) { s0 += __shfl_xor(s0, d, 64); s1 += __shfl_xor(s1, d, 64); }
            if (cg == 0) {
                if (r0 < n) {
                    int st = (r0 == 0) ? 0 : arr[r0 - 1];
                    nrm2[r0] = make_float2(1.0f / (sqrtf(s0) + 1e-12f),
                                           rsqrtf((float)(arr[r0] - st + 1)));
                }
                if (r1 < n) {
                    int st = arr[r1 - 1];
                    nrm2[r1] = make_float2(1.0f / (sqrtf(s1) + 1e-12f),
                                           rsqrtf((float)(arr[r1] - st + 1)));
                }
            }
        }
        __syncthreads();
    }
}

// ---------------- edge pass: wave/node, 8 edge-groups x 8 lanes ----------------
// lane: g = lane>>3 (edge group), s = lane&7 (covers row elems [8s,8s+8)).
//   agg[node] = dinv_c*(dinv_c*h_c + sum dinv_r*h_r)
//   yp[node]  = (h1 . wc[64:128,:])  (AGNN branch folded into classifier)

__global__ __launch_bounds__(256) void k_gather(const float* __restrict__ h,
    const int* __restrict__ arr, const int* __restrict__ csr,
    const float2* __restrict__ nrm2, const float* __restrict__ beta_p,
    const float* __restrict__ wc,
    float* __restrict__ agg, float2* __restrict__ yp, int n)
{
    int node = blockIdx.x * 4 + (threadIdx.x >> 6);
    if (node >= n) return;
    int lane = threadIdx.x & 63;
    int g = lane >> 3, s = lane & 7;
    float beta = beta_p[0];
    const float4* hrow = (const float4*)(h + (size_t)node * 64);
    float4 hcA = hrow[2 * s];
    float4 hcB = hrow[2 * s + 1];
    float ss = hcA.x*hcA.x + hcA.y*hcA.y + hcA.z*hcA.z + hcA.w*hcA.w
             + hcB.x*hcB.x + hcB.y*hcB.y + hcB.z*hcB.z + hcB.w*hcB.w;
#pragma unroll
    for (int d = 1; d < 8; d <<= 1) ss += __shfl_xor(ss, d, 64);
    float2 nc = nrm2[node];
    float rnc = nc.x, dc = nc.y;
    float wself = expf(beta * ss * rnc * rnc);
    float4 aA = make_float4(0.f,0.f,0.f,0.f), aB = aA, nA = aA, nB = aA;
    float denom = 0.f;
    if (g == 0) {
        aA = make_float4(dc*hcA.x, dc*hcA.y, dc*hcA.z, dc*hcA.w);
        aB = make_float4(dc*hcB.x, dc*hcB.y, dc*hcB.z, dc*hcB.w);
        nA = make_float4(wself*hcA.x, wself*hcA.y, wself*hcA.z, wself*hcA.w);
        nB = make_float4(wself*hcB.x, wself*hcB.y, wself*hcB.z, wself*hcB.w);
        denom = wself;
    }
    int start = (node == 0) ? 0 : arr[node - 1];
    int end = arr[node];
#pragma unroll 1
    for (int k0 = start; k0 < end; k0 += 64) {
        int m = min(64, end - k0);
        int idx = 0; float rv = 0.f, dv = 0.f;
        if (lane < m) {
            idx = csr[k0 + lane];
            float2 nd = nrm2[idx];
            rv = nd.x; dv = nd.y;
        }
        int ei = __shfl(idx, g, 64);
        const float4* rp = (const float4*)(h + (size_t)ei * 64);
        float4 cA = rp[2 * s], cB = rp[2 * s + 1];
#pragma unroll 1
        for (int k = 0; k < m; k += 8) {
            float4 hA = cA, hB = cB;
            if (k + 8 < m) {
                int e2 = __shfl(idx, k + 8 + g, 64);
                const float4* p2 = (const float4*)(h + (size_t)e2 * 64);
                cA = p2[2 * s]; cB = p2[2 * s + 1];
            }
            float rnr = __shfl(rv, k + g, 64);
            float dvr = __shfl(dv, k + g, 64);
            float p = hA.x*hcA.x + hA.y*hcA.y + hA.z*hcA.z + hA.w*hcA.w
                    + hB.x*hcB.x + hB.y*hcB.y + hB.z*hcB.z + hB.w*hcB.w;
#pragma unroll
            for (int d = 1; d < 8; d <<= 1) p += __shfl_xor(p, d, 64);
            bool act = (k + g) < m;
            float w   = act ? expf(beta * p * rnc * rnr) : 0.f;
            float dve = act ? dvr : 0.f;
            aA.x = fmaf(dve, hA.x, aA.x); aA.y = fmaf(dve, hA.y, aA.y);
            aA.z = fmaf(dve, hA.z, aA.z); aA.w = fmaf(dve, hA.w, aA.w);
            aB.x = fmaf(dve, hB.x, aB.x); aB.y = fmaf(dve, hB.y, aB.y);
            aB.z = fmaf(dve, hB.z, aB.z); aB.w = fmaf(dve, hB.w, aB.w);
            nA.x = fmaf(w, hA.x, nA.x); nA.y = fmaf(w, hA.y, nA.y);
            nA.z = fmaf(w, hA.z, nA.z); nA.w = fmaf(w, hA.w, nA.w);
            nB.x = fmaf(w, hB.x, nB.x); nB.y = fmaf(w, hB.y, nB.y);
            nB.z = fmaf(w, hB.z, nB.z); nB.w = fmaf(w, hB.w, nB.w);
            denom += w;
        }
    }
    // combine the 8 edge groups (butterfly over lane bits 3,4,5)
#pragma unroll
    for (int d = 8; d < 64; d <<= 1) {
        aA.x += __shfl_xor(aA.x, d, 64); aA.y += __shfl_xor(aA.y, d, 64);
        aA.z += __shfl_xor(aA.z, d, 64); aA.w += __shfl_xor(aA.w, d, 64);
        aB.x += __shfl_xor(aB.x, d, 64); aB.y += __shfl_xor(aB.y, d, 64);
        aB.z += __shfl_xor(aB.z, d, 64); aB.w += __shfl_xor(aB.w, d, 64);
        nA.x += __shfl_xor(nA.x, d, 64); nA.y += __shfl_xor(nA.y, d, 64);
        nA.z += __shfl_xor(nA.z, d, 64); nA.w += __shfl_xor(nA.w, d, 64);
        nB.x += __shfl_xor(nB.x, d, 64); nB.y += __shfl_xor(nB.y, d, 64);
        nB.z += __shfl_xor(nB.z, d, 64); nB.w += __shfl_xor(nB.w, d, 64);
        denom += __shfl_xor(denom, d, 64);
    }
    if (g == 0) {
        float4* op = (float4*)(agg + (size_t)node * 64);
        op[2 * s]     = make_float4(dc*aA.x, dc*aA.y, dc*aA.z, dc*aA.w);
        op[2 * s + 1] = make_float4(dc*aB.x, dc*aB.y, dc*aB.z, dc*aB.w);
    }
    float inv = 1.0f / denom;
    float cx = 0.f, cy = 0.f;
#pragma unroll
    for (int j = 0; j < 4; j++) {
        float2 wa = ((const float2*)wc)[64 + 8 * s + j];
        float2 wb = ((const float2*)wc)[64 + 8 * s + 4 + j];
        float va = (&nA.x)[j], vb = (&nB.x)[j];
        cx = fmaf(va, wa.x, cx); cx = fmaf(vb, wb.x, cx);
        cy = fmaf(va, wa.y, cy); cy = fmaf(vb, wb.y, cy);
    }
    cx *= inv; cy *= inv;
#pragma unroll
    for (int d = 1; d < 8; d <<= 1) { cx += __shfl_xor(cx, d, 64); cy += __shfl_xor(cy, d, 64); }
    if (lane == 0) yp[node] = make_float2(cx, cy);
}

// ---------------- epilogue: 512 thr (launch_bounds(512,2) -> 256 VGPR cap),
// 64-row tiles, option-A core, 8 waves/CU ----------------

__global__ __launch_bounds__(512, 2) void k_epi(const float* __restrict__ agg,
    const float* __restrict__ h, const float2* __restrict__ yp,
    const float* __restrict__ wg1, const float* __restrict__ bg1,
    const float* __restrict__ wg2, const float* __restrict__ bg2,
    const float* __restrict__ wf,  const float* __restrict__ bf,
    const float* __restrict__ wx,  const float* __restrict__ bx,
    const float* __restrict__ wc,  const float* __restrict__ bc,
    float* __restrict__ y, int n, int ntiles)
{
    __shared__ float wg1s[4096], wg2s[4096], wfs[4096], wxs[4096];
    __shared__ float bg1s[64], bg2s[64], bfs[64], bxs[64], wcs[256], bcs2[2];
    __shared__ float A[64][68], H[64][68], C[64][68], D[64][68];
    __shared__ float ll[64][2];
    int t = threadIdx.x;
    for (int i = t; i < 4096; i += 512) { wg1s[i] = wg1[i]; wg2s[i] = wg2[i]; wfs[i] = wf[i]; wxs[i] = wx[i]; }
    if (t < 64) { bg1s[t] = bg1[t]; bg2s[t] = bg2[t]; bfs[t] = bf[t]; bxs[t] = bx[t]; }
    if (t < 256) wcs[t] = wc[t];
    if (t < 2) bcs2[t] = bc[t];
    __syncthreads();
    int cg = t & 15, rg = t >> 4;     // rg 0..31 -> rows {2rg,2rg+1}
    int tr = t >> 3, tp = t & 7;      // final phase: 64 rows x 8 lanes
    for (int tile = blockIdx.x; tile < ntiles; tile += gridDim.x) {
        int row0 = tile * 64;
        load_rows64_512(agg, row0, n, A, t);
        load_rows64_512(h,   row0, n, H, t);
        __syncthreads();
        float xp0[4], xp1[4];
        gemm_core(H, wxs, bxs, rg, cg, xp0, xp1);
#pragma unroll
        for (int j = 0; j < 4; j++) { xp0[j] = tanhf(xp0[j]); xp1[j] = tanhf(xp1[j]); }
        gemm_lds<0>(A, wg1s, bg1s, C, rg, cg);   // C = f0
        gemm_lds<0>(A, wg2s, bg2s, D, rg, cg);   // D = f1
        __syncthreads();
        {
            float a0[4], a1[4], t0, t1;
            gemm_core(C, wfs, bfs, rg, cg, a0, a1);
            t0 = 0.f; t1 = 0.f;
#pragma unroll
            for (int j = 0; j < 4; j++) {
                t0 = fmaf(tanhf(a0[j]), xp0[j], t0);
                t1 = fmaf(tanhf(a1[j]), xp1[j], t1);
            }
#pragma unroll
            for (int d = 1; d < 16; d <<= 1) { t0 += __shfl_xor(t0, d, 64); t1 += __shfl_xor(t1, d, 64); }
            if (cg == 0) { ll[2 * rg][0] = t0; ll[2 * rg + 1][0] = t1; }
            gemm_core(D, wfs, bfs, rg, cg, a0, a1);
            t0 = 0.f; t1 = 0.f;
#pragma unroll
            for (int j = 0; j < 4; j++) {
                t0 = fmaf(tanhf(a0[j]), xp0[j], t0);
                t1 = fmaf(tanhf(a1[j]), xp1[j], t1);
            }
#pragma unroll
            for (int d = 1; d < 16; d <<= 1) { t0 += __shfl_xor(t0, d, 64); t1 += __shfl_xor(t1, d, 64); }
            if (cg == 0) { ll[2 * rg][1] = t0; ll[2 * rg + 1][1] = t1; }
        }
        __syncthreads();
        {
            int row = row0 + tr;
            if (row < n) {
                float l0 = ll[tr][0], l1 = ll[tr][1];
                float mx = fmaxf(l0, l1);
                float e0 = expf(l0 - mx), e1 = expf(l1 - mx);
                float inv = 1.0f / (e0 + e1);
                float s0 = e0 * inv, s1 = e1 * inv;
                float y0 = 0.f, y1 = 0.f;
#pragma unroll
                for (int u = 0; u < 8; u++) {
                    int j = tp * 8 + u;
                    float res = s0 * C[tr][j] + s1 * D[tr][j];
                    y0 = fmaf(res, wcs[j * 2 + 0], y0);
                    y1 = fmaf(res, wcs[j * 2 + 1], y1);
                }
#pragma unroll
                for (int d = 1; d < 8; d <<= 1) { y0 += __shfl_xor(y0, d, 64); y1 += __shfl_xor(y1, d, 64); }
                if (tp == 0) {
                    float2 ypv = yp[row];
                    y[(size_t)row * 2 + 0] = y0 + ypv.x + bcs2[0];
                    y[(size_t)row * 2 + 1] = y1 + ypv.y + bcs2[1];
                }
            }
        }
        __syncthreads();
    }
}

extern "C" void kernel_launch(void* const* d_in, const int* in_sizes, int n_in,
                              void* d_out, int out_size, void* d_ws, size_t ws_size,
                              hipStream_t stream)
{
    const float* x    = (const float*)d_in[0];
    const int*   ei   = (const int*)d_in[1];
    const float* w1   = (const float*)d_in[2];
    const float* b1   = (const float*)d_in[3];
    const float* w2   = (const float*)d_in[4];
    const float* b2   = (const float*)d_in[5];
    const float* w3   = (const float*)d_in[6];
    const float* b3   = (const float*)d_in[7];
    const float* wg1  = (const float*)d_in[8];
    const float* bg1  = (const float*)d_in[9];
    const float* wg2  = (const float*)d_in[10];
    const float* bg2  = (const float*)d_in[11];
    const float* beta = (const float*)d_in[12];
    const float* wf   = (const float*)d_in[13];
    const float* bf   = (const float*)d_in[14];
    const float* wx   = (const float*)d_in[15];
    const float* bx   = (const float*)d_in[16];
    const float* wc   = (const float*)d_in[17];
    const float* bc   = (const float*)d_in[18];
    float* y = (float*)d_out;

    int n = in_sizes[0] / 64;     // 100000
    int e = in_sizes[1] / 2;      // 1600000
    const int* row = ei;
    const int* col = ei + e;

    // workspace ~34MB
    char* p = (char*)d_ws;
    auto alloc = [&](size_t bytes) { char* q = p; p += (bytes + 255) & ~(size_t)255; return q; };
    float*  h    = (float*)alloc((size_t)n * 64 * 4);    // 25.6MB
    int*    csr  = (int*)alloc((size_t)e * 4);           // 6.4MB
    float2* nrm2 = (float2*)alloc((size_t)n * 8);        // 0.8MB
    int*    arr  = (int*)alloc((size_t)(n + 1) * 4);     // 0.4MB
    float2* yp   = (float2*)alloc((size_t)n * 8);        // 0.8MB

    // agg reuses x's buffer: x is consumed by k_mlp before k_gather writes it,
    // and the harness restores d_in from pristine before every launch.
    float* agg = (float*)d_in[0];

    int ntiles_e = (n + 63) / 64;

    k_zero<<<(n + 256) / 256, 256, 0, stream>>>(arr, n + 1);
    k_count<<<(e + 255) / 256, 256, 0, stream>>>(col, arr, e);
    k_scan<<<1, 1024, 0, stream>>>(arr, n);
    k_fill<<<(e + 255) / 256, 256, 0, stream>>>(row, col, arr, csr, e);
    k_mlp<<<800, 256, 0, stream>>>(x, w1, b1, w2, b2, w3, b3, arr, h, nrm2, n);
    k_gather<<<(n + 3) / 4, 256, 0, stream>>>(h, arr, csr, nrm2, beta, wc, agg, yp, n);
    k_epi<<<256, 512, 0, stream>>>(agg, h, yp, wg1, bg1, wg2, bg2, wf, bf, wx, bx, wc, bc, y, n, ntiles_e);
}

// Round 8
// 843.778 us; speedup vs baseline: 3.3224x; 3.3224x over previous
//
#include <hip/hip_runtime.h>
#include <math.h>

// N=100000 nodes, E=1600000 edges, HID=64, C=2, fp32.
// Hard-won constraints (R2-R7):
//  * Weights staged in LDS before unrolled gemm cores (global-weight unrolled
//    loads -> VGPR hoist -> spill; R2/R3 WRITE 1-3GB).
//  * option-A epi demand ~232 VGPR; option-C (4x4) >256 -> spill (R6).
//  * 512-thread blocks are unusable: plain LB(512) caps VGPR at 128 (R5),
//    and LB(512,2) ALSO produced a 128 cap on this toolchain (R7) -> spill.
//    Only 256-thread blocks with the default 256 cap are spill-free.
// R8: k_epi keeps the R4 spill-free shape but diets LDS 100.5KB -> ~69KB so
// 2 blocks/CU fit (8 waves/CU): wx+H-tile removed (new k_xp pass writes
// xp=tanh(h@wx+bx) in-place over h, dead after k_gather), f1 tile aliased
// into A via a register round-trip.

__device__ __forceinline__ void fma4(float (&acc)[4], float a, const float4& w) {
    acc[0] = fmaf(a, w.x, acc[0]);
    acc[1] = fmaf(a, w.y, acc[1]);
    acc[2] = fmaf(a, w.z, acc[2]);
    acc[3] = fmaf(a, w.w, acc[3]);
}

// 256 threads: stage 32 rows x 64 cols (8 floats/thread)
__device__ __forceinline__ void load_rows32(const float* __restrict__ src, int row0, int n,
                                            float (*dst)[68], int t)
{
    int e = t * 8;
    int r = e >> 6, i = e & 63;
    int grow = row0 + r;
    float4 v0 = make_float4(0.f, 0.f, 0.f, 0.f), v1 = v0;
    if (grow < n) {
        const float* p = src + (size_t)grow * 64 + i;
        v0 = *(const float4*)p;
        v1 = *(const float4*)(p + 4);
    }
    *(float4*)&dst[r][i]     = v0;
    *(float4*)&dst[r][i + 4] = v1;
}

// ---- option A core: 2 rows x 4 cols ----
__device__ __forceinline__ void gemm_core(const float (*in)[68], const float* w,
                                          const float* b, int rg, int cg,
                                          float (&acc0)[4], float (&acc1)[4])
{
#pragma unroll
    for (int dc = 0; dc < 4; dc++) { float bb = b[4*cg + dc]; acc0[dc] = bb; acc1[dc] = bb; }
    const int r0 = 2 * rg, r1 = 2 * rg + 1;
#pragma unroll
    for (int i = 0; i < 64; i += 4) {
        float4 a0 = *(const float4*)&in[r0][i];
        float4 a1 = *(const float4*)&in[r1][i];
        float4 q0 = *(const float4*)&w[(i + 0) * 64 + 4 * cg];
        float4 q1 = *(const float4*)&w[(i + 1) * 64 + 4 * cg];
        float4 q2 = *(const float4*)&w[(i + 2) * 64 + 4 * cg];
        float4 q3 = *(const float4*)&w[(i + 3) * 64 + 4 * cg];
        fma4(acc0, a0.x, q0); fma4(acc0, a0.y, q1); fma4(acc0, a0.z, q2); fma4(acc0, a0.w, q3);
        fma4(acc1, a1.x, q0); fma4(acc1, a1.y, q1); fma4(acc1, a1.z, q2); fma4(acc1, a1.w, q3);
    }
}

template <int MODE>  // 0=none, 1=relu, 2=tanh
__device__ __forceinline__ void gemm_lds(const float (*in)[68], const float* w,
                                         const float* b, float (*out)[68],
                                         int rg, int cg)
{
    float a0[4], a1[4];
    gemm_core(in, w, b, rg, cg, a0, a1);
#pragma unroll
    for (int dc = 0; dc < 4; dc++) {
        float v0 = a0[dc], v1 = a1[dc];
        if (MODE == 1) { v0 = fmaxf(v0, 0.f); v1 = fmaxf(v1, 0.f); }
        if (MODE == 2) { v0 = tanhf(v0); v1 = tanhf(v1); }
        a0[dc] = v0; a1[dc] = v1;
    }
    *(float4*)&out[2 * rg][4 * cg]     = make_float4(a0[0], a0[1], a0[2], a0[3]);
    *(float4*)&out[2 * rg + 1][4 * cg] = make_float4(a1[0], a1[1], a1[2], a1[3]);
}

// ---------------- CSR build (single arr[n+1]) ----------------

__global__ __launch_bounds__(256) void k_zero(int* __restrict__ arr, int n1)
{
    int i = blockIdx.x * 256 + threadIdx.x;
    if (i < n1) arr[i] = 0;
}

__global__ __launch_bounds__(256) void k_count(const int* __restrict__ col, int* __restrict__ arr, int e)
{
    int i = blockIdx.x * 256 + threadIdx.x;
    if (i < e) atomicAdd(&arr[col[i]], 1);
}

__global__ __launch_bounds__(1024) void k_scan(int* __restrict__ arr, int n)
{
    __shared__ int s[1024];
    int t = threadIdx.x;
    int chunk = (n + 1023) / 1024;
    int start = t * chunk;
    int end = min(n, start + chunk);
    int tot = 0;
    for (int i = start; i < end; i++) tot += arr[i];
    s[t] = tot;
    __syncthreads();
    for (int d = 1; d < 1024; d <<= 1) {
        int v = (t >= d) ? s[t - d] : 0;
        __syncthreads();
        s[t] += v;
        __syncthreads();
    }
    int run = s[t] - tot;
    for (int i = start; i < end; i++) { int v = arr[i]; arr[i] = run; run += v; }
    if (t == 1023) arr[n] = s[1023];
}

// after fill: arr[c] = end of segment c ; start(c) = c ? arr[c-1] : 0
__global__ __launch_bounds__(256) void k_fill(const int* __restrict__ row, const int* __restrict__ col,
                                              int* __restrict__ arr, int* __restrict__ csr, int e)
{
    int i = blockIdx.x * 256 + threadIdx.x;
    if (i < e) {
        int c = col[i];
        int p = atomicAdd(&arr[c], 1);
        csr[p] = row[i];
    }
}

// ---------------- node MLP + fused per-node scalars ----------------

__global__ __launch_bounds__(256) void k_mlp(const float* __restrict__ x,
    const float* __restrict__ w1, const float* __restrict__ b1,
    const float* __restrict__ w2, const float* __restrict__ b2,
    const float* __restrict__ w3, const float* __restrict__ b3,
    const int* __restrict__ arr, float* __restrict__ h,
    float2* __restrict__ nrm2, int n)
{
    __shared__ float w1s[4096], w2s[4096], w3s[4096];
    __shared__ float b1s[64], b2s[64], b3s[64];
    __shared__ float xs[32][68], hs[32][68];
    int t = threadIdx.x;
    for (int i = t; i < 4096; i += 256) { w1s[i] = w1[i]; w2s[i] = w2[i]; w3s[i] = w3[i]; }
    if (t < 64) { b1s[t] = b1[t]; b2s[t] = b2[t]; b3s[t] = b3[t]; }
    __syncthreads();
    int cg = t & 15, rg = t >> 4;
    for (int row0 = blockIdx.x * 32; row0 < n; row0 += gridDim.x * 32) {
        load_rows32(x, row0, n, xs, t);
        __syncthreads();
        gemm_lds<1>(xs, w1s, b1s, hs, rg, cg);
        __syncthreads();
        gemm_lds<1>(hs, w2s, b2s, xs, rg, cg);
        __syncthreads();
        {
            float a0[4], a1[4];
            gemm_core(xs, w3s, b3s, rg, cg, a0, a1);
            int r0 = row0 + 2 * rg, r1 = r0 + 1;
            if (r0 < n) *(float4*)&h[(size_t)r0 * 64 + 4 * cg] = make_float4(a0[0], a0[1], a0[2], a0[3]);
            if (r1 < n) *(float4*)&h[(size_t)r1 * 64 + 4 * cg] = make_float4(a1[0], a1[1], a1[2], a1[3]);
            float s0 = a0[0]*a0[0] + a0[1]*a0[1] + a0[2]*a0[2] + a0[3]*a0[3];
            float s1 = a1[0]*a1[0] + a1[1]*a1[1] + a1[2]*a1[2] + a1[3]*a1[3];
#pragma unroll
            for (int d = 1; d < 16; d <<= 1) { s0 += __shfl_xor(s0, d, 64); s1 += __shfl_xor(s1, d, 64); }
            if (cg == 0) {
                if (r0 < n) {
                    int st = (r0 == 0) ? 0 : arr[r0 - 1];
                    nrm2[r0] = make_float2(1.0f / (sqrtf(s0) + 1e-12f),
                                           rsqrtf((float)(arr[r0] - st + 1)));
                }
                if (r1 < n) {
                    int st = arr[r1 - 1];
                    nrm2[r1] = make_float2(1.0f / (sqrtf(s1) + 1e-12f),
                                           rsqrtf((float)(arr[r1] - st + 1)));
                }
            }
        }
        __syncthreads();
    }
}

// ---------------- edge pass: wave/node, 8 edge-groups x 8 lanes ----------------

__global__ __launch_bounds__(256) void k_gather(const float* __restrict__ h,
    const int* __restrict__ arr, const int* __restrict__ csr,
    const float2* __restrict__ nrm2, const float* __restrict__ beta_p,
    const float* __restrict__ wc,
    float* __restrict__ agg, float2* __restrict__ yp, int n)
{
    int node = blockIdx.x * 4 + (threadIdx.x >> 6);
    if (node >= n) return;
    int lane = threadIdx.x & 63;
    int g = lane >> 3, s = lane & 7;
    float beta = beta_p[0];
    const float4* hrow = (const float4*)(h + (size_t)node * 64);
    float4 hcA = hrow[2 * s];
    float4 hcB = hrow[2 * s + 1];
    float ss = hcA.x*hcA.x + hcA.y*hcA.y + hcA.z*hcA.z + hcA.w*hcA.w
             + hcB.x*hcB.x + hcB.y*hcB.y + hcB.z*hcB.z + hcB.w*hcB.w;
#pragma unroll
    for (int d = 1; d < 8; d <<= 1) ss += __shfl_xor(ss, d, 64);
    float2 nc = nrm2[node];
    float rnc = nc.x, dc = nc.y;
    float wself = expf(beta * ss * rnc * rnc);
    float4 aA = make_float4(0.f,0.f,0.f,0.f), aB = aA, nA = aA, nB = aA;
    float denom = 0.f;
    if (g == 0) {
        aA = make_float4(dc*hcA.x, dc*hcA.y, dc*hcA.z, dc*hcA.w);
        aB = make_float4(dc*hcB.x, dc*hcB.y, dc*hcB.z, dc*hcB.w);
        nA = make_float4(wself*hcA.x, wself*hcA.y, wself*hcA.z, wself*hcA.w);
        nB = make_float4(wself*hcB.x, wself*hcB.y, wself*hcB.z, wself*hcB.w);
        denom = wself;
    }
    int start = (node == 0) ? 0 : arr[node - 1];
    int end = arr[node];
#pragma unroll 1
    for (int k0 = start; k0 < end; k0 += 64) {
        int m = min(64, end - k0);
        int idx = 0; float rv = 0.f, dv = 0.f;
        if (lane < m) {
            idx = csr[k0 + lane];
            float2 nd = nrm2[idx];
            rv = nd.x; dv = nd.y;
        }
        int ei = __shfl(idx, g, 64);
        const float4* rp = (const float4*)(h + (size_t)ei * 64);
        float4 cA = rp[2 * s], cB = rp[2 * s + 1];
#pragma unroll 1
        for (int k = 0; k < m; k += 8) {
            float4 hA = cA, hB = cB;
            if (k + 8 < m) {
                int e2 = __shfl(idx, k + 8 + g, 64);
                const float4* p2 = (const float4*)(h + (size_t)e2 * 64);
                cA = p2[2 * s]; cB = p2[2 * s + 1];
            }
            float rnr = __shfl(rv, k + g, 64);
            float dvr = __shfl(dv, k + g, 64);
            float p = hA.x*hcA.x + hA.y*hcA.y + hA.z*hcA.z + hA.w*hcA.w
                    + hB.x*hcB.x + hB.y*hcB.y + hB.z*hcB.z + hB.w*hcB.w;
#pragma unroll
            for (int d = 1; d < 8; d <<= 1) p += __shfl_xor(p, d, 64);
            bool act = (k + g) < m;
            float w   = act ? expf(beta * p * rnc * rnr) : 0.f;
            float dve = act ? dvr : 0.f;
            aA.x = fmaf(dve, hA.x, aA.x); aA.y = fmaf(dve, hA.y, aA.y);
            aA.z = fmaf(dve, hA.z, aA.z); aA.w = fmaf(dve, hA.w, aA.w);
            aB.x = fmaf(dve, hB.x, aB.x); aB.y = fmaf(dve, hB.y, aB.y);
            aB.z = fmaf(dve, hB.z, aB.z); aB.w = fmaf(dve, hB.w, aB.w);
            nA.x = fmaf(w, hA.x, nA.x); nA.y = fmaf(w, hA.y, nA.y);
            nA.z = fmaf(w, hA.z, nA.z); nA.w = fmaf(w, hA.w, nA.w);
            nB.x = fmaf(w, hB.x, nB.x); nB.y = fmaf(w, hB.y, nB.y);
            nB.z = fmaf(w, hB.z, nB.z); nB.w = fmaf(w, hB.w, nB.w);
            denom += w;
        }
    }
#pragma unroll
    for (int d = 8; d < 64; d <<= 1) {
        aA.x += __shfl_xor(aA.x, d, 64); aA.y += __shfl_xor(aA.y, d, 64);
        aA.z += __shfl_xor(aA.z, d, 64); aA.w += __shfl_xor(aA.w, d, 64);
        aB.x += __shfl_xor(aB.x, d, 64); aB.y += __shfl_xor(aB.y, d, 64);
        aB.z += __shfl_xor(aB.z, d, 64); aB.w += __shfl_xor(aB.w, d, 64);
        nA.x += __shfl_xor(nA.x, d, 64); nA.y += __shfl_xor(nA.y, d, 64);
        nA.z += __shfl_xor(nA.z, d, 64); nA.w += __shfl_xor(nA.w, d, 64);
        nB.x += __shfl_xor(nB.x, d, 64); nB.y += __shfl_xor(nB.y, d, 64);
        nB.z += __shfl_xor(nB.z, d, 64); nB.w += __shfl_xor(nB.w, d, 64);
        denom += __shfl_xor(denom, d, 64);
    }
    if (g == 0) {
        float4* op = (float4*)(agg + (size_t)node * 64);
        op[2 * s]     = make_float4(dc*aA.x, dc*aA.y, dc*aA.z, dc*aA.w);
        op[2 * s + 1] = make_float4(dc*aB.x, dc*aB.y, dc*aB.z, dc*aB.w);
    }
    float inv = 1.0f / denom;
    float cx = 0.f, cy = 0.f;
#pragma unroll
    for (int j = 0; j < 4; j++) {
        float2 wa = ((const float2*)wc)[64 + 8 * s + j];
        float2 wb = ((const float2*)wc)[64 + 8 * s + 4 + j];
        float va = (&nA.x)[j], vb = (&nB.x)[j];
        cx = fmaf(va, wa.x, cx); cx = fmaf(vb, wb.x, cx);
        cy = fmaf(va, wa.y, cy); cy = fmaf(vb, wb.y, cy);
    }
    cx *= inv; cy *= inv;
#pragma unroll
    for (int d = 1; d < 8; d <<= 1) { cx += __shfl_xor(cx, d, 64); cy += __shfl_xor(cy, d, 64); }
    if (lane == 0) yp[node] = make_float2(cx, cy);
}

// ---------------- xp pass: h <- tanh(h@wx + bx) in place ----------------
// Runs AFTER k_gather (which needs the true h). Disjoint row tiles per block.

__global__ __launch_bounds__(256) void k_xp(float* __restrict__ h,
    const float* __restrict__ wx, const float* __restrict__ bx, int n)
{
    __shared__ float wxs[4096];
    __shared__ float bxs[64];
    __shared__ float xs[32][68];
    int t = threadIdx.x;
    for (int i = t; i < 4096; i += 256) wxs[i] = wx[i];
    if (t < 64) bxs[t] = bx[t];
    __syncthreads();
    int cg = t & 15, rg = t >> 4;
    for (int row0 = blockIdx.x * 32; row0 < n; row0 += gridDim.x * 32) {
        load_rows32(h, row0, n, xs, t);
        __syncthreads();
        float a0[4], a1[4];
        gemm_core(xs, wxs, bxs, rg, cg, a0, a1);
#pragma unroll
        for (int j = 0; j < 4; j++) { a0[j] = tanhf(a0[j]); a1[j] = tanhf(a1[j]); }
        int r0 = row0 + 2 * rg, r1 = r0 + 1;
        if (r0 < n) *(float4*)&h[(size_t)r0 * 64 + 4 * cg] = make_float4(a0[0], a0[1], a0[2], a0[3]);
        if (r1 < n) *(float4*)&h[(size_t)r1 * 64 + 4 * cg] = make_float4(a1[0], a1[1], a1[2], a1[3]);
        __syncthreads();   // xs reads done before next tile's load
    }
}

// ---------------- epilogue: 256 thr, 32-row tiles, ~69KB LDS -> 2 blocks/CU ----------------
// A = agg tile -> later aliased to f1 ; C = f0 ; xp read per-thread from global.

__global__ __launch_bounds__(256) void k_epi(const float* __restrict__ agg,
    const float* __restrict__ xpb, const float2* __restrict__ yp,
    const float* __restrict__ wg1, const float* __restrict__ bg1,
    const float* __restrict__ wg2, const float* __restrict__ bg2,
    const float* __restrict__ wf,  const float* __restrict__ bf,
    const float* __restrict__ wc,  const float* __restrict__ bc,
    float* __restrict__ y, int n, int ntiles)
{
    __shared__ float wg1s[4096], wg2s[4096], wfs[4096];
    __shared__ float bg1s[64], bg2s[64], bfs[64], wcs[256], bcs2[2];
    __shared__ float A[32][68], C[32][68];
    __shared__ float ll[32][2];
    int t = threadIdx.x;
    for (int i = t; i < 4096; i += 256) { wg1s[i] = wg1[i]; wg2s[i] = wg2[i]; wfs[i] = wf[i]; }
    if (t < 64) { bg1s[t] = bg1[t]; bg2s[t] = bg2[t]; bfs[t] = bf[t]; }
    wcs[t] = wc[t];
    if (t < 2) bcs2[t] = bc[t];
    __syncthreads();
    int cg = t & 15, rg = t >> 4;   // rows {2rg, 2rg+1}, cols 4cg..4cg+3
    int tr = t >> 3, tp = t & 7;    // final phase: 32 rows x 8 lanes
    for (int tile = blockIdx.x; tile < ntiles; tile += gridDim.x) {
        int row0 = tile * 32;
        load_rows32(agg, row0, n, A, t);
        __syncthreads();
        int r0 = row0 + 2 * rg, r1 = r0 + 1;
        // xp slice for this thread, straight from global (L2-hot)
        float4 xq0 = make_float4(0.f,0.f,0.f,0.f), xq1 = xq0;
        if (r0 < n) xq0 = *(const float4*)&xpb[(size_t)r0 * 64 + 4 * cg];
        if (r1 < n) xq1 = *(const float4*)&xpb[(size_t)r1 * 64 + 4 * cg];
        // C = f0 = A@wg1+bg1
        gemm_lds<0>(A, wg1s, bg1s, C, rg, cg);
        // f1 via registers, then alias into A
        float d0[4], d1[4];
        gemm_core(A, wg2s, bg2s, rg, cg, d0, d1);
        __syncthreads();   // A reads + C writes complete
        *(float4*)&A[2 * rg][4 * cg]     = make_float4(d0[0], d0[1], d0[2], d0[3]);
        *(float4*)&A[2 * rg + 1][4 * cg] = make_float4(d1[0], d1[1], d1[2], d1[3]);
        __syncthreads();   // A-as-f1 visible
        // fused logits: l_k[row] = sum_j tanh((f_k@wf+bf)[row][j]) * xp[row][j]
        {
            float a0[4], a1[4], t0, t1;
            gemm_core(C, wfs, bfs, rg, cg, a0, a1);
            t0 = 0.f; t1 = 0.f;
            t0 = fmaf(tanhf(a0[0]), xq0.x, t0); t0 = fmaf(tanhf(a0[1]), xq0.y, t0);
            t0 = fmaf(tanhf(a0[2]), xq0.z, t0); t0 = fmaf(tanhf(a0[3]), xq0.w, t0);
            t1 = fmaf(tanhf(a1[0]), xq1.x, t1); t1 = fmaf(tanhf(a1[1]), xq1.y, t1);
            t1 = fmaf(tanhf(a1[2]), xq1.z, t1); t1 = fmaf(tanhf(a1[3]), xq1.w, t1);
#pragma unroll
            for (int d = 1; d < 16; d <<= 1) { t0 += __shfl_xor(t0, d, 64); t1 += __shfl_xor(t1, d, 64); }
            if (cg == 0) { ll[2 * rg][0] = t0; ll[2 * rg + 1][0] = t1; }
            gemm_core(A, wfs, bfs, rg, cg, a0, a1);
            t0 = 0.f; t1 = 0.f;
            t0 = fmaf(tanhf(a0[0]), xq0.x, t0); t0 = fmaf(tanhf(a0[1]), xq0.y, t0);
            t0 = fmaf(tanhf(a0[2]), xq0.z, t0); t0 = fmaf(tanhf(a0[3]), xq0.w, t0);
            t1 = fmaf(tanhf(a1[0]), xq1.x, t1); t1 = fmaf(tanhf(a1[1]), xq1.y, t1);
            t1 = fmaf(tanhf(a1[2]), xq1.z, t1); t1 = fmaf(tanhf(a1[3]), xq1.w, t1);
#pragma unroll
            for (int d = 1; d < 16; d <<= 1) { t0 += __shfl_xor(t0, d, 64); t1 += __shfl_xor(t1, d, 64); }
            if (cg == 0) { ll[2 * rg][1] = t0; ll[2 * rg + 1][1] = t1; }
        }
        __syncthreads();
        // softmax fusion + classifier: 32 rows x 8 lanes
        {
            int row = row0 + tr;
            if (row < n) {
                float l0 = ll[tr][0], l1 = ll[tr][1];
                float mx = fmaxf(l0, l1);
                float e0 = expf(l0 - mx), e1 = expf(l1 - mx);
                float inv = 1.0f / (e0 + e1);
                float s0 = e0 * inv, s1 = e1 * inv;
                float y0 = 0.f, y1 = 0.f;
#pragma unroll
                for (int u = 0; u < 8; u++) {
                    int j = tp * 8 + u;
                    float res = s0 * C[tr][j] + s1 * A[tr][j];
                    y0 = fmaf(res, wcs[j * 2 + 0], y0);
                    y1 = fmaf(res, wcs[j * 2 + 1], y1);
                }
#pragma unroll
                for (int d = 1; d < 8; d <<= 1) { y0 += __shfl_xor(y0, d, 64); y1 += __shfl_xor(y1, d, 64); }
                if (tp == 0) {
                    float2 ypv = yp[row];
                    y[(size_t)row * 2 + 0] = y0 + ypv.x + bcs2[0];
                    y[(size_t)row * 2 + 1] = y1 + ypv.y + bcs2[1];
                }
            }
        }
        __syncthreads();
    }
}

extern "C" void kernel_launch(void* const* d_in, const int* in_sizes, int n_in,
                              void* d_out, int out_size, void* d_ws, size_t ws_size,
                              hipStream_t stream)
{
    const float* x    = (const float*)d_in[0];
    const int*   ei   = (const int*)d_in[1];
    const float* w1   = (const float*)d_in[2];
    const float* b1   = (const float*)d_in[3];
    const float* w2   = (const float*)d_in[4];
    const float* b2   = (const float*)d_in[5];
    const float* w3   = (const float*)d_in[6];
    const float* b3   = (const float*)d_in[7];
    const float* wg1  = (const float*)d_in[8];
    const float* bg1  = (const float*)d_in[9];
    const float* wg2  = (const float*)d_in[10];
    const float* bg2  = (const float*)d_in[11];
    const float* beta = (const float*)d_in[12];
    const float* wf   = (const float*)d_in[13];
    const float* bf   = (const float*)d_in[14];
    const float* wx   = (const float*)d_in[15];
    const float* bx   = (const float*)d_in[16];
    const float* wc   = (const float*)d_in[17];
    const float* bc   = (const float*)d_in[18];
    float* y = (float*)d_out;

    int n = in_sizes[0] / 64;     // 100000
    int e = in_sizes[1] / 2;      // 1600000
    const int* row = ei;
    const int* col = ei + e;

    // workspace ~34MB
    char* p = (char*)d_ws;
    auto alloc = [&](size_t bytes) { char* q = p; p += (bytes + 255) & ~(size_t)255; return q; };
    float*  h    = (float*)alloc((size_t)n * 64 * 4);    // 25.6MB (h, then xp in-place)
    int*    csr  = (int*)alloc((size_t)e * 4);           // 6.4MB
    float2* nrm2 = (float2*)alloc((size_t)n * 8);        // 0.8MB
    int*    arr  = (int*)alloc((size_t)(n + 1) * 4);     // 0.4MB
    float2* yp   = (float2*)alloc((size_t)n * 8);        // 0.8MB

    // agg reuses x's buffer: x is consumed by k_mlp before k_gather writes it,
    // and the harness restores d_in from pristine before every launch.
    float* agg = (float*)d_in[0];

    int ntiles_e = (n + 31) / 32;   // 3125

    k_zero<<<(n + 256) / 256, 256, 0, stream>>>(arr, n + 1);
    k_count<<<(e + 255) / 256, 256, 0, stream>>>(col, arr, e);
    k_scan<<<1, 1024, 0, stream>>>(arr, n);
    k_fill<<<(e + 255) / 256, 256, 0, stream>>>(row, col, arr, csr, e);
    k_mlp<<<800, 256, 0, stream>>>(x, w1, b1, w2, b2, w3, b3, arr, h, nrm2, n);
    k_gather<<<(n + 3) / 4, 256, 0, stream>>>(h, arr, csr, nrm2, beta, wc, agg, yp, n);
    k_xp<<<800, 256, 0, stream>>>(h, wx, bx, n);
    k_epi<<<1024, 256, 0, stream>>>(agg, h, yp, wg1, bg1, wg2, bg2, wf, bf, wc, bc, y, n, ntiles_e);
}

// Round 9
// 692.011 us; speedup vs baseline: 4.0511x; 1.2193x over previous
//
#include <hip/hip_runtime.h>
#include <math.h>

// N=100000 nodes, E=1600000 edges, HID=64, C=2, fp32.
// Hard-won constraints (R2-R8):
//  * Weights staged in LDS before unrolled gemm cores (global-weight unrolled
//    loads -> VGPR hoist -> spill; R2/R3 WRITE 1-3GB).
//  * option-A epi demand ~224-232 VGPR; option-C (4x4) >256 -> spill (R6).
//  * 512-thread blocks unusable: LB(512) and LB(512,2) both cap VGPR at 128
//    on this toolchain (R5/R7) -> spill. Only 256-thread blocks (default 256
//    cap) are spill-free.
//  * k_epi at 67.5KB LDS -> 2 blocks/CU, 164us, no spill (R8).
// R9: the single-block k_scan was 165us (serial, one CU). Replaced with a
// 3-kernel hierarchical scan (chunk=512): ~20-30us total.

__device__ __forceinline__ void fma4(float (&acc)[4], float a, const float4& w) {
    acc[0] = fmaf(a, w.x, acc[0]);
    acc[1] = fmaf(a, w.y, acc[1]);
    acc[2] = fmaf(a, w.z, acc[2]);
    acc[3] = fmaf(a, w.w, acc[3]);
}

// 256 threads: stage 32 rows x 64 cols (8 floats/thread)
__device__ __forceinline__ void load_rows32(const float* __restrict__ src, int row0, int n,
                                            float (*dst)[68], int t)
{
    int e = t * 8;
    int r = e >> 6, i = e & 63;
    int grow = row0 + r;
    float4 v0 = make_float4(0.f, 0.f, 0.f, 0.f), v1 = v0;
    if (grow < n) {
        const float* p = src + (size_t)grow * 64 + i;
        v0 = *(const float4*)p;
        v1 = *(const float4*)(p + 4);
    }
    *(float4*)&dst[r][i]     = v0;
    *(float4*)&dst[r][i + 4] = v1;
}

// ---- option A core: 2 rows x 4 cols ----
__device__ __forceinline__ void gemm_core(const float (*in)[68], const float* w,
                                          const float* b, int rg, int cg,
                                          float (&acc0)[4], float (&acc1)[4])
{
#pragma unroll
    for (int dc = 0; dc < 4; dc++) { float bb = b[4*cg + dc]; acc0[dc] = bb; acc1[dc] = bb; }
    const int r0 = 2 * rg, r1 = 2 * rg + 1;
#pragma unroll
    for (int i = 0; i < 64; i += 4) {
        float4 a0 = *(const float4*)&in[r0][i];
        float4 a1 = *(const float4*)&in[r1][i];
        float4 q0 = *(const float4*)&w[(i + 0) * 64 + 4 * cg];
        float4 q1 = *(const float4*)&w[(i + 1) * 64 + 4 * cg];
        float4 q2 = *(const float4*)&w[(i + 2) * 64 + 4 * cg];
        float4 q3 = *(const float4*)&w[(i + 3) * 64 + 4 * cg];
        fma4(acc0, a0.x, q0); fma4(acc0, a0.y, q1); fma4(acc0, a0.z, q2); fma4(acc0, a0.w, q3);
        fma4(acc1, a1.x, q0); fma4(acc1, a1.y, q1); fma4(acc1, a1.z, q2); fma4(acc1, a1.w, q3);
    }
}

template <int MODE>  // 0=none, 1=relu, 2=tanh
__device__ __forceinline__ void gemm_lds(const float (*in)[68], const float* w,
                                         const float* b, float (*out)[68],
                                         int rg, int cg)
{
    float a0[4], a1[4];
    gemm_core(in, w, b, rg, cg, a0, a1);
#pragma unroll
    for (int dc = 0; dc < 4; dc++) {
        float v0 = a0[dc], v1 = a1[dc];
        if (MODE == 1) { v0 = fmaxf(v0, 0.f); v1 = fmaxf(v1, 0.f); }
        if (MODE == 2) { v0 = tanhf(v0); v1 = tanhf(v1); }
        a0[dc] = v0; a1[dc] = v1;
    }
    *(float4*)&out[2 * rg][4 * cg]     = make_float4(a0[0], a0[1], a0[2], a0[3]);
    *(float4*)&out[2 * rg + 1][4 * cg] = make_float4(a1[0], a1[1], a1[2], a1[3]);
}

// ---------------- CSR build (single arr[n+1], hierarchical scan) ----------------

__global__ __launch_bounds__(256) void k_zero(int* __restrict__ arr, int n1)
{
    int i = blockIdx.x * 256 + threadIdx.x;
    if (i < n1) arr[i] = 0;
}

__global__ __launch_bounds__(256) void k_count(const int* __restrict__ col, int* __restrict__ arr, int e)
{
    int i = blockIdx.x * 256 + threadIdx.x;
    if (i < e) atomicAdd(&arr[col[i]], 1);
}

// stage A: per-block (chunk=512) exclusive scan in place + block total -> part[b]
__global__ __launch_bounds__(256) void k_scan_a(int* __restrict__ arr, int* __restrict__ part, int n)
{
    __shared__ int s[256];
    int b = blockIdx.x, t = threadIdx.x;
    int i0 = b * 512 + 2 * t, i1 = i0 + 1;
    int v0 = (i0 < n) ? arr[i0] : 0;
    int v1 = (i1 < n) ? arr[i1] : 0;
    int sum = v0 + v1;
    s[t] = sum;
    __syncthreads();
    for (int d = 1; d < 256; d <<= 1) {
        int v = (t >= d) ? s[t - d] : 0;
        __syncthreads();
        s[t] += v;
        __syncthreads();
    }
    int excl = s[t] - sum;
    if (i0 < n) arr[i0] = excl;
    if (i1 < n) arr[i1] = excl + v0;
    if (t == 255) part[b] = s[255];
}

// stage B: single block exclusive-scans the block totals (nb <= 256)
__global__ __launch_bounds__(256) void k_scan_b(int* __restrict__ part, int nb)
{
    __shared__ int s[256];
    int t = threadIdx.x;
    int v = (t < nb) ? part[t] : 0;
    s[t] = v;
    __syncthreads();
    for (int d = 1; d < 256; d <<= 1) {
        int u = (t >= d) ? s[t - d] : 0;
        __syncthreads();
        s[t] += u;
        __syncthreads();
    }
    if (t < nb) part[t] = s[t] - v;
}

// stage C: add block prefix
__global__ __launch_bounds__(256) void k_scan_c(int* __restrict__ arr, const int* __restrict__ part, int n)
{
    int i = blockIdx.x * 256 + threadIdx.x;
    if (i < n) arr[i] += part[i >> 9];
}

// after fill: arr[c] = end of segment c ; start(c) = c ? arr[c-1] : 0
__global__ __launch_bounds__(256) void k_fill(const int* __restrict__ row, const int* __restrict__ col,
                                              int* __restrict__ arr, int* __restrict__ csr, int e)
{
    int i = blockIdx.x * 256 + threadIdx.x;
    if (i < e) {
        int c = col[i];
        int p = atomicAdd(&arr[c], 1);
        csr[p] = row[i];
    }
}

// ---------------- node MLP + fused per-node scalars ----------------

__global__ __launch_bounds__(256) void k_mlp(const float* __restrict__ x,
    const float* __restrict__ w1, const float* __restrict__ b1,
    const float* __restrict__ w2, const float* __restrict__ b2,
    const float* __restrict__ w3, const float* __restrict__ b3,
    const int* __restrict__ arr, float* __restrict__ h,
    float2* __restrict__ nrm2, int n)
{
    __shared__ float w1s[4096], w2s[4096], w3s[4096];
    __shared__ float b1s[64], b2s[64], b3s[64];
    __shared__ float xs[32][68], hs[32][68];
    int t = threadIdx.x;
    for (int i = t; i < 4096; i += 256) { w1s[i] = w1[i]; w2s[i] = w2[i]; w3s[i] = w3[i]; }
    if (t < 64) { b1s[t] = b1[t]; b2s[t] = b2[t]; b3s[t] = b3[t]; }
    __syncthreads();
    int cg = t & 15, rg = t >> 4;
    for (int row0 = blockIdx.x * 32; row0 < n; row0 += gridDim.x * 32) {
        load_rows32(x, row0, n, xs, t);
        __syncthreads();
        gemm_lds<1>(xs, w1s, b1s, hs, rg, cg);
        __syncthreads();
        gemm_lds<1>(hs, w2s, b2s, xs, rg, cg);
        __syncthreads();
        {
            float a0[4], a1[4];
            gemm_core(xs, w3s, b3s, rg, cg, a0, a1);
            int r0 = row0 + 2 * rg, r1 = r0 + 1;
            if (r0 < n) *(float4*)&h[(size_t)r0 * 64 + 4 * cg] = make_float4(a0[0], a0[1], a0[2], a0[3]);
            if (r1 < n) *(float4*)&h[(size_t)r1 * 64 + 4 * cg] = make_float4(a1[0], a1[1], a1[2], a1[3]);
            float s0 = a0[0]*a0[0] + a0[1]*a0[1] + a0[2]*a0[2] + a0[3]*a0[3];
            float s1 = a1[0]*a1[0] + a1[1]*a1[1] + a1[2]*a1[2] + a1[3]*a1[3];
#pragma unroll
            for (int d = 1; d < 16; d <<= 1) { s0 += __shfl_xor(s0, d, 64); s1 += __shfl_xor(s1, d, 64); }
            if (cg == 0) {
                if (r0 < n) {
                    int st = (r0 == 0) ? 0 : arr[r0 - 1];
                    nrm2[r0] = make_float2(1.0f / (sqrtf(s0) + 1e-12f),
                                           rsqrtf((float)(arr[r0] - st + 1)));
                }
                if (r1 < n) {
                    int st = arr[r1 - 1];
                    nrm2[r1] = make_float2(1.0f / (sqrtf(s1) + 1e-12f),
                                           rsqrtf((float)(arr[r1] - st + 1)));
                }
            }
        }
        __syncthreads();
    }
}

// ---------------- edge pass: wave/node, 8 edge-groups x 8 lanes ----------------

__global__ __launch_bounds__(256) void k_gather(const float* __restrict__ h,
    const int* __restrict__ arr, const int* __restrict__ csr,
    const float2* __restrict__ nrm2, const float* __restrict__ beta_p,
    const float* __restrict__ wc,
    float* __restrict__ agg, float2* __restrict__ yp, int n)
{
    int node = blockIdx.x * 4 + (threadIdx.x >> 6);
    if (node >= n) return;
    int lane = threadIdx.x & 63;
    int g = lane >> 3, s = lane & 7;
    float beta = beta_p[0];
    const float4* hrow = (const float4*)(h + (size_t)node * 64);
    float4 hcA = hrow[2 * s];
    float4 hcB = hrow[2 * s + 1];
    float ss = hcA.x*hcA.x + hcA.y*hcA.y + hcA.z*hcA.z + hcA.w*hcA.w
             + hcB.x*hcB.x + hcB.y*hcB.y + hcB.z*hcB.z + hcB.w*hcB.w;
#pragma unroll
    for (int d = 1; d < 8; d <<= 1) ss += __shfl_xor(ss, d, 64);
    float2 nc = nrm2[node];
    float rnc = nc.x, dc = nc.y;
    float wself = expf(beta * ss * rnc * rnc);
    float4 aA = make_float4(0.f,0.f,0.f,0.f), aB = aA, nA = aA, nB = aA;
    float denom = 0.f;
    if (g == 0) {
        aA = make_float4(dc*hcA.x, dc*hcA.y, dc*hcA.z, dc*hcA.w);
        aB = make_float4(dc*hcB.x, dc*hcB.y, dc*hcB.z, dc*hcB.w);
        nA = make_float4(wself*hcA.x, wself*hcA.y, wself*hcA.z, wself*hcA.w);
        nB = make_float4(wself*hcB.x, wself*hcB.y, wself*hcB.z, wself*hcB.w);
        denom = wself;
    }
    int start = (node == 0) ? 0 : arr[node - 1];
    int end = arr[node];
#pragma unroll 1
    for (int k0 = start; k0 < end; k0 += 64) {
        int m = min(64, end - k0);
        int idx = 0; float rv = 0.f, dv = 0.f;
        if (lane < m) {
            idx = csr[k0 + lane];
            float2 nd = nrm2[idx];
            rv = nd.x; dv = nd.y;
        }
        int ei = __shfl(idx, g, 64);
        const float4* rp = (const float4*)(h + (size_t)ei * 64);
        float4 cA = rp[2 * s], cB = rp[2 * s + 1];
#pragma unroll 1
        for (int k = 0; k < m; k += 8) {
            float4 hA = cA, hB = cB;
            if (k + 8 < m) {
                int e2 = __shfl(idx, k + 8 + g, 64);
                const float4* p2 = (const float4*)(h + (size_t)e2 * 64);
                cA = p2[2 * s]; cB = p2[2 * s + 1];
            }
            float rnr = __shfl(rv, k + g, 64);
            float dvr = __shfl(dv, k + g, 64);
            float p = hA.x*hcA.x + hA.y*hcA.y + hA.z*hcA.z + hA.w*hcA.w
                    + hB.x*hcB.x + hB.y*hcB.y + hB.z*hcB.z + hB.w*hcB.w;
#pragma unroll
            for (int d = 1; d < 8; d <<= 1) p += __shfl_xor(p, d, 64);
            bool act = (k + g) < m;
            float w   = act ? expf(beta * p * rnc * rnr) : 0.f;
            float dve = act ? dvr : 0.f;
            aA.x = fmaf(dve, hA.x, aA.x); aA.y = fmaf(dve, hA.y, aA.y);
            aA.z = fmaf(dve, hA.z, aA.z); aA.w = fmaf(dve, hA.w, aA.w);
            aB.x = fmaf(dve, hB.x, aB.x); aB.y = fmaf(dve, hB.y, aB.y);
            aB.z = fmaf(dve, hB.z, aB.z); aB.w = fmaf(dve, hB.w, aB.w);
            nA.x = fmaf(w, hA.x, nA.x); nA.y = fmaf(w, hA.y, nA.y);
            nA.z = fmaf(w, hA.z, nA.z); nA.w = fmaf(w, hA.w, nA.w);
            nB.x = fmaf(w, hB.x, nB.x); nB.y = fmaf(w, hB.y, nB.y);
            nB.z = fmaf(w, hB.z, nB.z); nB.w = fmaf(w, hB.w, nB.w);
            denom += w;
        }
    }
#pragma unroll
    for (int d = 8; d < 64; d <<= 1) {
        aA.x += __shfl_xor(aA.x, d, 64); aA.y += __shfl_xor(aA.y, d, 64);
        aA.z += __shfl_xor(aA.z, d, 64); aA.w += __shfl_xor(aA.w, d, 64);
        aB.x += __shfl_xor(aB.x, d, 64); aB.y += __shfl_xor(aB.y, d, 64);
        aB.z += __shfl_xor(aB.z, d, 64); aB.w += __shfl_xor(aB.w, d, 64);
        nA.x += __shfl_xor(nA.x, d, 64); nA.y += __shfl_xor(nA.y, d, 64);
        nA.z += __shfl_xor(nA.z, d, 64); nA.w += __shfl_xor(nA.w, d, 64);
        nB.x += __shfl_xor(nB.x, d, 64); nB.y += __shfl_xor(nB.y, d, 64);
        nB.z += __shfl_xor(nB.z, d, 64); nB.w += __shfl_xor(nB.w, d, 64);
        denom += __shfl_xor(denom, d, 64);
    }
    if (g == 0) {
        float4* op = (float4*)(agg + (size_t)node * 64);
        op[2 * s]     = make_float4(dc*aA.x, dc*aA.y, dc*aA.z, dc*aA.w);
        op[2 * s + 1] = make_float4(dc*aB.x, dc*aB.y, dc*aB.z, dc*aB.w);
    }
    float inv = 1.0f / denom;
    float cx = 0.f, cy = 0.f;
#pragma unroll
    for (int j = 0; j < 4; j++) {
        float2 wa = ((const float2*)wc)[64 + 8 * s + j];
        float2 wb = ((const float2*)wc)[64 + 8 * s + 4 + j];
        float va = (&nA.x)[j], vb = (&nB.x)[j];
        cx = fmaf(va, wa.x, cx); cx = fmaf(vb, wb.x, cx);
        cy = fmaf(va, wa.y, cy); cy = fmaf(vb, wb.y, cy);
    }
    cx *= inv; cy *= inv;
#pragma unroll
    for (int d = 1; d < 8; d <<= 1) { cx += __shfl_xor(cx, d, 64); cy += __shfl_xor(cy, d, 64); }
    if (lane == 0) yp[node] = make_float2(cx, cy);
}

// ---------------- xp pass: h <- tanh(h@wx + bx) in place ----------------

__global__ __launch_bounds__(256) void k_xp(float* __restrict__ h,
    const float* __restrict__ wx, const float* __restrict__ bx, int n)
{
    __shared__ float wxs[4096];
    __shared__ float bxs[64];
    __shared__ float xs[32][68];
    int t = threadIdx.x;
    for (int i = t; i < 4096; i += 256) wxs[i] = wx[i];
    if (t < 64) bxs[t] = bx[t];
    __syncthreads();
    int cg = t & 15, rg = t >> 4;
    for (int row0 = blockIdx.x * 32; row0 < n; row0 += gridDim.x * 32) {
        load_rows32(h, row0, n, xs, t);
        __syncthreads();
        float a0[4], a1[4];
        gemm_core(xs, wxs, bxs, rg, cg, a0, a1);
#pragma unroll
        for (int j = 0; j < 4; j++) { a0[j] = tanhf(a0[j]); a1[j] = tanhf(a1[j]); }
        int r0 = row0 + 2 * rg, r1 = r0 + 1;
        if (r0 < n) *(float4*)&h[(size_t)r0 * 64 + 4 * cg] = make_float4(a0[0], a0[1], a0[2], a0[3]);
        if (r1 < n) *(float4*)&h[(size_t)r1 * 64 + 4 * cg] = make_float4(a1[0], a1[1], a1[2], a1[3]);
        __syncthreads();
    }
}

// ---------------- epilogue: 256 thr, 32-row tiles, ~67.5KB LDS, 2 blocks/CU ----------------

__global__ __launch_bounds__(256) void k_epi(const float* __restrict__ agg,
    const float* __restrict__ xpb, const float2* __restrict__ yp,
    const float* __restrict__ wg1, const float* __restrict__ bg1,
    const float* __restrict__ wg2, const float* __restrict__ bg2,
    const float* __restrict__ wf,  const float* __restrict__ bf,
    const float* __restrict__ wc,  const float* __restrict__ bc,
    float* __restrict__ y, int n, int ntiles)
{
    __shared__ float wg1s[4096], wg2s[4096], wfs[4096];
    __shared__ float bg1s[64], bg2s[64], bfs[64], wcs[256], bcs2[2];
    __shared__ float A[32][68], C[32][68];
    __shared__ float ll[32][2];
    int t = threadIdx.x;
    for (int i = t; i < 4096; i += 256) { wg1s[i] = wg1[i]; wg2s[i] = wg2[i]; wfs[i] = wf[i]; }
    if (t < 64) { bg1s[t] = bg1[t]; bg2s[t] = bg2[t]; bfs[t] = bf[t]; }
    wcs[t] = wc[t];
    if (t < 2) bcs2[t] = bc[t];
    __syncthreads();
    int cg = t & 15, rg = t >> 4;
    int tr = t >> 3, tp = t & 7;
    for (int tile = blockIdx.x; tile < ntiles; tile += gridDim.x) {
        int row0 = tile * 32;
        load_rows32(agg, row0, n, A, t);
        __syncthreads();
        int r0 = row0 + 2 * rg, r1 = r0 + 1;
        float4 xq0 = make_float4(0.f,0.f,0.f,0.f), xq1 = xq0;
        if (r0 < n) xq0 = *(const float4*)&xpb[(size_t)r0 * 64 + 4 * cg];
        if (r1 < n) xq1 = *(const float4*)&xpb[(size_t)r1 * 64 + 4 * cg];
        gemm_lds<0>(A, wg1s, bg1s, C, rg, cg);          // C = f0
        float d0[4], d1[4];
        gemm_core(A, wg2s, bg2s, rg, cg, d0, d1);       // f1 in regs
        __syncthreads();
        *(float4*)&A[2 * rg][4 * cg]     = make_float4(d0[0], d0[1], d0[2], d0[3]);
        *(float4*)&A[2 * rg + 1][4 * cg] = make_float4(d1[0], d1[1], d1[2], d1[3]);
        __syncthreads();
        {
            float a0[4], a1[4], t0, t1;
            gemm_core(C, wfs, bfs, rg, cg, a0, a1);
            t0 = 0.f; t1 = 0.f;
            t0 = fmaf(tanhf(a0[0]), xq0.x, t0); t0 = fmaf(tanhf(a0[1]), xq0.y, t0);
            t0 = fmaf(tanhf(a0[2]), xq0.z, t0); t0 = fmaf(tanhf(a0[3]), xq0.w, t0);
            t1 = fmaf(tanhf(a1[0]), xq1.x, t1); t1 = fmaf(tanhf(a1[1]), xq1.y, t1);
            t1 = fmaf(tanhf(a1[2]), xq1.z, t1); t1 = fmaf(tanhf(a1[3]), xq1.w, t1);
#pragma unroll
            for (int d = 1; d < 16; d <<= 1) { t0 += __shfl_xor(t0, d, 64); t1 += __shfl_xor(t1, d, 64); }
            if (cg == 0) { ll[2 * rg][0] = t0; ll[2 * rg + 1][0] = t1; }
            gemm_core(A, wfs, bfs, rg, cg, a0, a1);
            t0 = 0.f; t1 = 0.f;
            t0 = fmaf(tanhf(a0[0]), xq0.x, t0); t0 = fmaf(tanhf(a0[1]), xq0.y, t0);
            t0 = fmaf(tanhf(a0[2]), xq0.z, t0); t0 = fmaf(tanhf(a0[3]), xq0.w, t0);
            t1 = fmaf(tanhf(a1[0]), xq1.x, t1); t1 = fmaf(tanhf(a1[1]), xq1.y, t1);
            t1 = fmaf(tanhf(a1[2]), xq1.z, t1); t1 = fmaf(tanhf(a1[3]), xq1.w, t1);
#pragma unroll
            for (int d = 1; d < 16; d <<= 1) { t0 += __shfl_xor(t0, d, 64); t1 += __shfl_xor(t1, d, 64); }
            if (cg == 0) { ll[2 * rg][1] = t0; ll[2 * rg + 1][1] = t1; }
        }
        __syncthreads();
        {
            int row = row0 + tr;
            if (row < n) {
                float l0 = ll[tr][0], l1 = ll[tr][1];
                float mx = fmaxf(l0, l1);
                float e0 = expf(l0 - mx), e1 = expf(l1 - mx);
                float inv = 1.0f / (e0 + e1);
                float s0 = e0 * inv, s1 = e1 * inv;
                float y0 = 0.f, y1 = 0.f;
#pragma unroll
                for (int u = 0; u < 8; u++) {
                    int j = tp * 8 + u;
                    float res = s0 * C[tr][j] + s1 * A[tr][j];
                    y0 = fmaf(res, wcs[j * 2 + 0], y0);
                    y1 = fmaf(res, wcs[j * 2 + 1], y1);
                }
#pragma unroll
                for (int d = 1; d < 8; d <<= 1) { y0 += __shfl_xor(y0, d, 64); y1 += __shfl_xor(y1, d, 64); }
                if (tp == 0) {
                    float2 ypv = yp[row];
                    y[(size_t)row * 2 + 0] = y0 + ypv.x + bcs2[0];
                    y[(size_t)row * 2 + 1] = y1 + ypv.y + bcs2[1];
                }
            }
        }
        __syncthreads();
    }
}

extern "C" void kernel_launch(void* const* d_in, const int* in_sizes, int n_in,
                              void* d_out, int out_size, void* d_ws, size_t ws_size,
                              hipStream_t stream)
{
    const float* x    = (const float*)d_in[0];
    const int*   ei   = (const int*)d_in[1];
    const float* w1   = (const float*)d_in[2];
    const float* b1   = (const float*)d_in[3];
    const float* w2   = (const float*)d_in[4];
    const float* b2   = (const float*)d_in[5];
    const float* w3   = (const float*)d_in[6];
    const float* b3   = (const float*)d_in[7];
    const float* wg1  = (const float*)d_in[8];
    const float* bg1  = (const float*)d_in[9];
    const float* wg2  = (const float*)d_in[10];
    const float* bg2  = (const float*)d_in[11];
    const float* beta = (const float*)d_in[12];
    const float* wf   = (const float*)d_in[13];
    const float* bf   = (const float*)d_in[14];
    const float* wx   = (const float*)d_in[15];
    const float* bx   = (const float*)d_in[16];
    const float* wc   = (const float*)d_in[17];
    const float* bc   = (const float*)d_in[18];
    float* y = (float*)d_out;

    int n = in_sizes[0] / 64;     // 100000
    int e = in_sizes[1] / 2;      // 1600000
    const int* row = ei;
    const int* col = ei + e;

    // workspace ~34MB
    char* p = (char*)d_ws;
    auto alloc = [&](size_t bytes) { char* q = p; p += (bytes + 255) & ~(size_t)255; return q; };
    float*  h    = (float*)alloc((size_t)n * 64 * 4);    // 25.6MB (h, then xp in-place)
    int*    csr  = (int*)alloc((size_t)e * 4);           // 6.4MB
    float2* nrm2 = (float2*)alloc((size_t)n * 8);        // 0.8MB
    int*    arr  = (int*)alloc((size_t)(n + 1) * 4);     // 0.4MB
    float2* yp   = (float2*)alloc((size_t)n * 8);        // 0.8MB
    int*    part = (int*)alloc(1024 * 4);                // scan block totals

    // agg reuses x's buffer (x dead after k_mlp; harness restores d_in).
    float* agg = (float*)d_in[0];

    int ntiles_e = (n + 31) / 32;          // 3125
    int nb = (n + 511) / 512;              // 196 scan blocks (<=256 required)

    k_zero<<<(n + 256) / 256, 256, 0, stream>>>(arr, n + 1);
    k_count<<<(e + 255) / 256, 256, 0, stream>>>(col, arr, e);
    k_scan_a<<<nb, 256, 0, stream>>>(arr, part, n);
    k_scan_b<<<1, 256, 0, stream>>>(part, nb);
    k_scan_c<<<(n + 255) / 256, 256, 0, stream>>>(arr, part, n);
    k_fill<<<(e + 255) / 256, 256, 0, stream>>>(row, col, arr, csr, e);
    k_mlp<<<800, 256, 0, stream>>>(x, w1, b1, w2, b2, w3, b3, arr, h, nrm2, n);
    k_gather<<<(n + 3) / 4, 256, 0, stream>>>(h, arr, csr, nrm2, beta, wc, agg, yp, n);
    k_xp<<<800, 256, 0, stream>>>(h, wx, bx, n);
    k_epi<<<1024, 256, 0, stream>>>(agg, h, yp, wg1, bg1, wg2, bg2, wf, bf, wc, bc, y, n, ntiles_e);
}

// Round 10
// 683.563 us; speedup vs baseline: 4.1011x; 1.0124x over previous
//
#include <hip/hip_runtime.h>
#include <math.h>

// N=100000 nodes, E=1600000 edges, HID=64, C=2, fp32.
// Hard-won constraints (R2-R9):
//  * Weights staged in LDS before unrolled gemm cores (global-weight unrolled
//    loads -> VGPR hoist -> spill; R2/R3 WRITE 1-3GB).
//  * option-A epi demand ~224-232 VGPR; option-C (4x4) >256 -> spill (R6).
//  * 512-thread blocks unusable (LB(512)/LB(512,2) both cap VGPR at 128 ->
//    spill, R5/R7). Only 256-thread blocks (default 256 cap) are spill-free.
//  * k_epi is LDS-throughput-bound (R9: 4 gemm cores = 384 ds_read_b128/thr/
//    tile ~= 94us LDS floor); occupancy doesn't move it.
// R10: algebraic fusion. p_k=tanh(f_k@wf+bf) == tanh(agg@(wg_k@wf)+(bg_k@wf+bf))
// and f_k@wc == agg@(wg_k@wc)+bg_k@wc, so f0/f1 are never materialized.
// k_pre precomputes W_k/c_k/u_k/v_k once; k_epi drops to 2 gemm cores + two
// 64->2 dots: half the LDS traffic, LDS 67.5KB -> ~42KB, 2 barriers/tile.

__device__ __forceinline__ void fma4(float (&acc)[4], float a, const float4& w) {
    acc[0] = fmaf(a, w.x, acc[0]);
    acc[1] = fmaf(a, w.y, acc[1]);
    acc[2] = fmaf(a, w.z, acc[2]);
    acc[3] = fmaf(a, w.w, acc[3]);
}

// 256 threads: stage 32 rows x 64 cols (8 floats/thread)
__device__ __forceinline__ void load_rows32(const float* __restrict__ src, int row0, int n,
                                            float (*dst)[68], int t)
{
    int e = t * 8;
    int r = e >> 6, i = e & 63;
    int grow = row0 + r;
    float4 v0 = make_float4(0.f, 0.f, 0.f, 0.f), v1 = v0;
    if (grow < n) {
        const float* p = src + (size_t)grow * 64 + i;
        v0 = *(const float4*)p;
        v1 = *(const float4*)(p + 4);
    }
    *(float4*)&dst[r][i]     = v0;
    *(float4*)&dst[r][i + 4] = v1;
}

// ---- option A core: 2 rows x 4 cols ----
__device__ __forceinline__ void gemm_core(const float (*in)[68], const float* w,
                                          const float* b, int rg, int cg,
                                          float (&acc0)[4], float (&acc1)[4])
{
#pragma unroll
    for (int dc = 0; dc < 4; dc++) { float bb = b[4*cg + dc]; acc0[dc] = bb; acc1[dc] = bb; }
    const int r0 = 2 * rg, r1 = 2 * rg + 1;
#pragma unroll
    for (int i = 0; i < 64; i += 4) {
        float4 a0 = *(const float4*)&in[r0][i];
        float4 a1 = *(const float4*)&in[r1][i];
        float4 q0 = *(const float4*)&w[(i + 0) * 64 + 4 * cg];
        float4 q1 = *(const float4*)&w[(i + 1) * 64 + 4 * cg];
        float4 q2 = *(const float4*)&w[(i + 2) * 64 + 4 * cg];
        float4 q3 = *(const float4*)&w[(i + 3) * 64 + 4 * cg];
        fma4(acc0, a0.x, q0); fma4(acc0, a0.y, q1); fma4(acc0, a0.z, q2); fma4(acc0, a0.w, q3);
        fma4(acc1, a1.x, q0); fma4(acc1, a1.y, q1); fma4(acc1, a1.z, q2); fma4(acc1, a1.w, q3);
    }
}

template <int MODE>  // 0=none, 1=relu, 2=tanh
__device__ __forceinline__ void gemm_lds(const float (*in)[68], const float* w,
                                         const float* b, float (*out)[68],
                                         int rg, int cg)
{
    float a0[4], a1[4];
    gemm_core(in, w, b, rg, cg, a0, a1);
#pragma unroll
    for (int dc = 0; dc < 4; dc++) {
        float v0 = a0[dc], v1 = a1[dc];
        if (MODE == 1) { v0 = fmaxf(v0, 0.f); v1 = fmaxf(v1, 0.f); }
        if (MODE == 2) { v0 = tanhf(v0); v1 = tanhf(v1); }
        a0[dc] = v0; a1[dc] = v1;
    }
    *(float4*)&out[2 * rg][4 * cg]     = make_float4(a0[0], a0[1], a0[2], a0[3]);
    *(float4*)&out[2 * rg + 1][4 * cg] = make_float4(a1[0], a1[1], a1[2], a1[3]);
}

// ---------------- CSR build (single arr[n+1], hierarchical scan) ----------------

__global__ __launch_bounds__(256) void k_zero(int* __restrict__ arr, int n1)
{
    int i = blockIdx.x * 256 + threadIdx.x;
    if (i < n1) arr[i] = 0;
}

__global__ __launch_bounds__(256) void k_count(const int* __restrict__ col, int* __restrict__ arr, int e)
{
    int i = blockIdx.x * 256 + threadIdx.x;
    if (i < e) atomicAdd(&arr[col[i]], 1);
}

__global__ __launch_bounds__(256) void k_scan_a(int* __restrict__ arr, int* __restrict__ part, int n)
{
    __shared__ int s[256];
    int b = blockIdx.x, t = threadIdx.x;
    int i0 = b * 512 + 2 * t, i1 = i0 + 1;
    int v0 = (i0 < n) ? arr[i0] : 0;
    int v1 = (i1 < n) ? arr[i1] : 0;
    int sum = v0 + v1;
    s[t] = sum;
    __syncthreads();
    for (int d = 1; d < 256; d <<= 1) {
        int v = (t >= d) ? s[t - d] : 0;
        __syncthreads();
        s[t] += v;
        __syncthreads();
    }
    int excl = s[t] - sum;
    if (i0 < n) arr[i0] = excl;
    if (i1 < n) arr[i1] = excl + v0;
    if (t == 255) part[b] = s[255];
}

__global__ __launch_bounds__(256) void k_scan_b(int* __restrict__ part, int nb)
{
    __shared__ int s[256];
    int t = threadIdx.x;
    int v = (t < nb) ? part[t] : 0;
    s[t] = v;
    __syncthreads();
    for (int d = 1; d < 256; d <<= 1) {
        int u = (t >= d) ? s[t - d] : 0;
        __syncthreads();
        s[t] += u;
        __syncthreads();
    }
    if (t < nb) part[t] = s[t] - v;
}

__global__ __launch_bounds__(256) void k_scan_c(int* __restrict__ arr, const int* __restrict__ part, int n)
{
    int i = blockIdx.x * 256 + threadIdx.x;
    if (i < n) arr[i] += part[i >> 9];
}

// after fill: arr[c] = end of segment c ; start(c) = c ? arr[c-1] : 0
__global__ __launch_bounds__(256) void k_fill(const int* __restrict__ row, const int* __restrict__ col,
                                              int* __restrict__ arr, int* __restrict__ csr, int e)
{
    int i = blockIdx.x * 256 + threadIdx.x;
    if (i < e) {
        int c = col[i];
        int p = atomicAdd(&arr[c], 1);
        csr[p] = row[i];
    }
}

// ---------------- weight precombination ----------------
// pre layout (floats): W0[4096] | W1[4096] | c0[64]@8192 | c1[64]@8256 |
//                      u0[128]@8320 | u1[128]@8448 | v[4]@8576
// W_k = wg_k @ wf ; c_k = bg_k@wf + bf ; u_k = wg_k@wc[0:64] ; v_k = bg_k@wc[0:64]

__global__ __launch_bounds__(256) void k_pre(
    const float* __restrict__ wg1, const float* __restrict__ bg1,
    const float* __restrict__ wg2, const float* __restrict__ bg2,
    const float* __restrict__ wf,  const float* __restrict__ bf,
    const float* __restrict__ wc,  float* __restrict__ pre)
{
    __shared__ float wfs[4096];
    __shared__ float wcs[128];
    int t = threadIdx.x;
    for (int i = t; i < 4096; i += 256) wfs[i] = wf[i];
    if (t < 128) wcs[t] = wc[t];   // classifier rows 0..63
    __syncthreads();
    int i = t & 63, jb = (t >> 6) * 16;
    float acc0[16], acc1[16];
#pragma unroll
    for (int j = 0; j < 16; j++) { acc0[j] = 0.f; acc1[j] = 0.f; }
#pragma unroll 1
    for (int k = 0; k < 64; k++) {
        float a = wg1[i * 64 + k];
        float b = wg2[i * 64 + k];
#pragma unroll
        for (int j = 0; j < 16; j++) {
            float w = wfs[k * 64 + jb + j];
            acc0[j] = fmaf(a, w, acc0[j]);
            acc1[j] = fmaf(b, w, acc1[j]);
        }
    }
#pragma unroll
    for (int j = 0; j < 16; j++) {
        pre[i * 64 + jb + j]        = acc0[j];
        pre[4096 + i * 64 + jb + j] = acc1[j];
    }
    if (t < 64) {
        float s0 = bf[t], s1 = bf[t];
#pragma unroll 1
        for (int m = 0; m < 64; m++) {
            s0 = fmaf(bg1[m], wfs[m * 64 + t], s0);
            s1 = fmaf(bg2[m], wfs[m * 64 + t], s1);
        }
        pre[8192 + t] = s0;
        pre[8256 + t] = s1;
        float u00 = 0.f, u01 = 0.f, u10 = 0.f, u11 = 0.f;
#pragma unroll 1
        for (int m = 0; m < 64; m++) {
            float g1 = wg1[t * 64 + m], g2 = wg2[t * 64 + m];
            u00 = fmaf(g1, wcs[m * 2 + 0], u00);
            u01 = fmaf(g1, wcs[m * 2 + 1], u01);
            u10 = fmaf(g2, wcs[m * 2 + 0], u10);
            u11 = fmaf(g2, wcs[m * 2 + 1], u11);
        }
        pre[8320 + t * 2]     = u00;
        pre[8320 + t * 2 + 1] = u01;
        pre[8448 + t * 2]     = u10;
        pre[8448 + t * 2 + 1] = u11;
    }
    if (t == 0) {
        float v00 = 0.f, v01 = 0.f, v10 = 0.f, v11 = 0.f;
#pragma unroll 1
        for (int m = 0; m < 64; m++) {
            v00 = fmaf(bg1[m], wcs[m * 2 + 0], v00);
            v01 = fmaf(bg1[m], wcs[m * 2 + 1], v01);
            v10 = fmaf(bg2[m], wcs[m * 2 + 0], v10);
            v11 = fmaf(bg2[m], wcs[m * 2 + 1], v11);
        }
        pre[8576] = v00; pre[8577] = v01; pre[8578] = v10; pre[8579] = v11;
    }
}

// ---------------- node MLP + fused per-node scalars ----------------

__global__ __launch_bounds__(256) void k_mlp(const float* __restrict__ x,
    const float* __restrict__ w1, const float* __restrict__ b1,
    const float* __restrict__ w2, const float* __restrict__ b2,
    const float* __restrict__ w3, const float* __restrict__ b3,
    const int* __restrict__ arr, float* __restrict__ h,
    float2* __restrict__ nrm2, int n)
{
    __shared__ float w1s[4096], w2s[4096], w3s[4096];
    __shared__ float b1s[64], b2s[64], b3s[64];
    __shared__ float xs[32][68], hs[32][68];
    int t = threadIdx.x;
    for (int i = t; i < 4096; i += 256) { w1s[i] = w1[i]; w2s[i] = w2[i]; w3s[i] = w3[i]; }
    if (t < 64) { b1s[t] = b1[t]; b2s[t] = b2[t]; b3s[t] = b3[t]; }
    __syncthreads();
    int cg = t & 15, rg = t >> 4;
    for (int row0 = blockIdx.x * 32; row0 < n; row0 += gridDim.x * 32) {
        load_rows32(x, row0, n, xs, t);
        __syncthreads();
        gemm_lds<1>(xs, w1s, b1s, hs, rg, cg);
        __syncthreads();
        gemm_lds<1>(hs, w2s, b2s, xs, rg, cg);
        __syncthreads();
        {
            float a0[4], a1[4];
            gemm_core(xs, w3s, b3s, rg, cg, a0, a1);
            int r0 = row0 + 2 * rg, r1 = r0 + 1;
            if (r0 < n) *(float4*)&h[(size_t)r0 * 64 + 4 * cg] = make_float4(a0[0], a0[1], a0[2], a0[3]);
            if (r1 < n) *(float4*)&h[(size_t)r1 * 64 + 4 * cg] = make_float4(a1[0], a1[1], a1[2], a1[3]);
            float s0 = a0[0]*a0[0] + a0[1]*a0[1] + a0[2]*a0[2] + a0[3]*a0[3];
            float s1 = a1[0]*a1[0] + a1[1]*a1[1] + a1[2]*a1[2] + a1[3]*a1[3];
#pragma unroll
            for (int d = 1; d < 16; d <<= 1) { s0 += __shfl_xor(s0, d, 64); s1 += __shfl_xor(s1, d, 64); }
            if (cg == 0) {
                if (r0 < n) {
                    int st = (r0 == 0) ? 0 : arr[r0 - 1];
                    nrm2[r0] = make_float2(1.0f / (sqrtf(s0) + 1e-12f),
                                           rsqrtf((float)(arr[r0] - st + 1)));
                }
                if (r1 < n) {
                    int st = arr[r1 - 1];
                    nrm2[r1] = make_float2(1.0f / (sqrtf(s1) + 1e-12f),
                                           rsqrtf((float)(arr[r1] - st + 1)));
                }
            }
        }
        __syncthreads();
    }
}

// ---------------- edge pass: wave/node, 8 edge-groups x 8 lanes ----------------

__global__ __launch_bounds__(256) void k_gather(const float* __restrict__ h,
    const int* __restrict__ arr, const int* __restrict__ csr,
    const float2* __restrict__ nrm2, const float* __restrict__ beta_p,
    const float* __restrict__ wc,
    float* __restrict__ agg, float2* __restrict__ yp, int n)
{
    int node = blockIdx.x * 4 + (threadIdx.x >> 6);
    if (node >= n) return;
    int lane = threadIdx.x & 63;
    int g = lane >> 3, s = lane & 7;
    float beta = beta_p[0];
    const float4* hrow = (const float4*)(h + (size_t)node * 64);
    float4 hcA = hrow[2 * s];
    float4 hcB = hrow[2 * s + 1];
    float ss = hcA.x*hcA.x + hcA.y*hcA.y + hcA.z*hcA.z + hcA.w*hcA.w
             + hcB.x*hcB.x + hcB.y*hcB.y + hcB.z*hcB.z + hcB.w*hcB.w;
#pragma unroll
    for (int d = 1; d < 8; d <<= 1) ss += __shfl_xor(ss, d, 64);
    float2 nc = nrm2[node];
    float rnc = nc.x, dc = nc.y;
    float wself = expf(beta * ss * rnc * rnc);
    float4 aA = make_float4(0.f,0.f,0.f,0.f), aB = aA, nA = aA, nB = aA;
    float denom = 0.f;
    if (g == 0) {
        aA = make_float4(dc*hcA.x, dc*hcA.y, dc*hcA.z, dc*hcA.w);
        aB = make_float4(dc*hcB.x, dc*hcB.y, dc*hcB.z, dc*hcB.w);
        nA = make_float4(wself*hcA.x, wself*hcA.y, wself*hcA.z, wself*hcA.w);
        nB = make_float4(wself*hcB.x, wself*hcB.y, wself*hcB.z, wself*hcB.w);
        denom = wself;
    }
    int start = (node == 0) ? 0 : arr[node - 1];
    int end = arr[node];
#pragma unroll 1
    for (int k0 = start; k0 < end; k0 += 64) {
        int m = min(64, end - k0);
        int idx = 0; float rv = 0.f, dv = 0.f;
        if (lane < m) {
            idx = csr[k0 + lane];
            float2 nd = nrm2[idx];
            rv = nd.x; dv = nd.y;
        }
        int ei = __shfl(idx, g, 64);
        const float4* rp = (const float4*)(h + (size_t)ei * 64);
        float4 cA = rp[2 * s], cB = rp[2 * s + 1];
#pragma unroll 1
        for (int k = 0; k < m; k += 8) {
            float4 hA = cA, hB = cB;
            if (k + 8 < m) {
                int e2 = __shfl(idx, k + 8 + g, 64);
                const float4* p2 = (const float4*)(h + (size_t)e2 * 64);
                cA = p2[2 * s]; cB = p2[2 * s + 1];
            }
            float rnr = __shfl(rv, k + g, 64);
            float dvr = __shfl(dv, k + g, 64);
            float p = hA.x*hcA.x + hA.y*hcA.y + hA.z*hcA.z + hA.w*hcA.w
                    + hB.x*hcB.x + hB.y*hcB.y + hB.z*hcB.z + hB.w*hcB.w;
#pragma unroll
            for (int d = 1; d < 8; d <<= 1) p += __shfl_xor(p, d, 64);
            bool act = (k + g) < m;
            float w   = act ? expf(beta * p * rnc * rnr) : 0.f;
            float dve = act ? dvr : 0.f;
            aA.x = fmaf(dve, hA.x, aA.x); aA.y = fmaf(dve, hA.y, aA.y);
            aA.z = fmaf(dve, hA.z, aA.z); aA.w = fmaf(dve, hA.w, aA.w);
            aB.x = fmaf(dve, hB.x, aB.x); aB.y = fmaf(dve, hB.y, aB.y);
            aB.z = fmaf(dve, hB.z, aB.z); aB.w = fmaf(dve, hB.w, aB.w);
            nA.x = fmaf(w, hA.x, nA.x); nA.y = fmaf(w, hA.y, nA.y);
            nA.z = fmaf(w, hA.z, nA.z); nA.w = fmaf(w, hA.w, nA.w);
            nB.x = fmaf(w, hB.x, nB.x); nB.y = fmaf(w, hB.y, nB.y);
            nB.z = fmaf(w, hB.z, nB.z); nB.w = fmaf(w, hB.w, nB.w);
            denom += w;
        }
    }
#pragma unroll
    for (int d = 8; d < 64; d <<= 1) {
        aA.x += __shfl_xor(aA.x, d, 64); aA.y += __shfl_xor(aA.y, d, 64);
        aA.z += __shfl_xor(aA.z, d, 64); aA.w += __shfl_xor(aA.w, d, 64);
        aB.x += __shfl_xor(aB.x, d, 64); aB.y += __shfl_xor(aB.y, d, 64);
        aB.z += __shfl_xor(aB.z, d, 64); aB.w += __shfl_xor(aB.w, d, 64);
        nA.x += __shfl_xor(nA.x, d, 64); nA.y += __shfl_xor(nA.y, d, 64);
        nA.z += __shfl_xor(nA.z, d, 64); nA.w += __shfl_xor(nA.w, d, 64);
        nB.x += __shfl_xor(nB.x, d, 64); nB.y += __shfl_xor(nB.y, d, 64);
        nB.z += __shfl_xor(nB.z, d, 64); nB.w += __shfl_xor(nB.w, d, 64);
        denom += __shfl_xor(denom, d, 64);
    }
    if (g == 0) {
        float4* op = (float4*)(agg + (size_t)node * 64);
        op[2 * s]     = make_float4(dc*aA.x, dc*aA.y, dc*aA.z, dc*aA.w);
        op[2 * s + 1] = make_float4(dc*aB.x, dc*aB.y, dc*aB.z, dc*aB.w);
    }
    float inv = 1.0f / denom;
    float cx = 0.f, cy = 0.f;
#pragma unroll
    for (int j = 0; j < 4; j++) {
        float2 wa = ((const float2*)wc)[64 + 8 * s + j];
        float2 wb = ((const float2*)wc)[64 + 8 * s + 4 + j];
        float va = (&nA.x)[j], vb = (&nB.x)[j];
        cx = fmaf(va, wa.x, cx); cx = fmaf(vb, wb.x, cx);
        cy = fmaf(va, wa.y, cy); cy = fmaf(vb, wb.y, cy);
    }
    cx *= inv; cy *= inv;
#pragma unroll
    for (int d = 1; d < 8; d <<= 1) { cx += __shfl_xor(cx, d, 64); cy += __shfl_xor(cy, d, 64); }
    if (lane == 0) yp[node] = make_float2(cx, cy);
}

// ---------------- xp pass: h <- tanh(h@wx + bx) in place ----------------

__global__ __launch_bounds__(256) void k_xp(float* __restrict__ h,
    const float* __restrict__ wx, const float* __restrict__ bx, int n)
{
    __shared__ float wxs[4096];
    __shared__ float bxs[64];
    __shared__ float xs[32][68];
    int t = threadIdx.x;
    for (int i = t; i < 4096; i += 256) wxs[i] = wx[i];
    if (t < 64) bxs[t] = bx[t];
    __syncthreads();
    int cg = t & 15, rg = t >> 4;
    for (int row0 = blockIdx.x * 32; row0 < n; row0 += gridDim.x * 32) {
        load_rows32(h, row0, n, xs, t);
        __syncthreads();
        float a0[4], a1[4];
        gemm_core(xs, wxs, bxs, rg, cg, a0, a1);
#pragma unroll
        for (int j = 0; j < 4; j++) { a0[j] = tanhf(a0[j]); a1[j] = tanhf(a1[j]); }
        int r0 = row0 + 2 * rg, r1 = r0 + 1;
        if (r0 < n) *(float4*)&h[(size_t)r0 * 64 + 4 * cg] = make_float4(a0[0], a0[1], a0[2], a0[3]);
        if (r1 < n) *(float4*)&h[(size_t)r1 * 64 + 4 * cg] = make_float4(a1[0], a1[1], a1[2], a1[3]);
        __syncthreads();
    }
}

// ---------------- epilogue (combined weights): 2 gemm cores + 64->2 dots ----------------
// l_k[row] = sum_j tanh((agg@W_k + c_k)[row][j]) * xp[row][j]
// z_k[row][c] = (agg . u_k[:,c]) + v_k[c]
// y[row] = s0*z0 + s1*z1 + yp[row] + bc   (softmax over l0,l1)

__global__ __launch_bounds__(256) void k_epi(const float* __restrict__ agg,
    const float* __restrict__ xpb, const float2* __restrict__ yp,
    const float* __restrict__ pre, const float* __restrict__ bc,
    float* __restrict__ y, int n, int ntiles)
{
    __shared__ float W0s[4096], W1s[4096];
    __shared__ float c0s[64], c1s[64], us[256], vs[4], bcs[2];
    __shared__ float A[32][68];
    int t = threadIdx.x;
    for (int i = t; i < 4096; i += 256) { W0s[i] = pre[i]; W1s[i] = pre[4096 + i]; }
    if (t < 64) { c0s[t] = pre[8192 + t]; c1s[t] = pre[8256 + t]; }
    us[t] = pre[8320 + t];
    if (t < 4) vs[t] = pre[8576 + t];
    if (t < 2) bcs[t] = bc[t];
    __syncthreads();
    int cg = t & 15, rg = t >> 4;
    for (int tile = blockIdx.x; tile < ntiles; tile += gridDim.x) {
        int row0 = tile * 32;
        load_rows32(agg, row0, n, A, t);
        __syncthreads();
        int r0g = row0 + 2 * rg, r1g = r0g + 1;
        float4 xq0 = make_float4(0.f,0.f,0.f,0.f), xq1 = xq0;
        if (r0g < n) xq0 = *(const float4*)&xpb[(size_t)r0g * 64 + 4 * cg];
        if (r1g < n) xq1 = *(const float4*)&xpb[(size_t)r1g * 64 + 4 * cg];
        float a0[4], a1[4];
        // filter 0 logit partials
        gemm_core(A, W0s, c0s, rg, cg, a0, a1);
        float l00 = 0.f, l01 = 0.f;
        l00 = fmaf(tanhf(a0[0]), xq0.x, l00); l00 = fmaf(tanhf(a0[1]), xq0.y, l00);
        l00 = fmaf(tanhf(a0[2]), xq0.z, l00); l00 = fmaf(tanhf(a0[3]), xq0.w, l00);
        l01 = fmaf(tanhf(a1[0]), xq1.x, l01); l01 = fmaf(tanhf(a1[1]), xq1.y, l01);
        l01 = fmaf(tanhf(a1[2]), xq1.z, l01); l01 = fmaf(tanhf(a1[3]), xq1.w, l01);
        // filter 1 logit partials
        gemm_core(A, W1s, c1s, rg, cg, a0, a1);
        float l10 = 0.f, l11 = 0.f;
        l10 = fmaf(tanhf(a0[0]), xq0.x, l10); l10 = fmaf(tanhf(a0[1]), xq0.y, l10);
        l10 = fmaf(tanhf(a0[2]), xq0.z, l10); l10 = fmaf(tanhf(a0[3]), xq0.w, l10);
        l11 = fmaf(tanhf(a1[0]), xq1.x, l11); l11 = fmaf(tanhf(a1[1]), xq1.y, l11);
        l11 = fmaf(tanhf(a1[2]), xq1.z, l11); l11 = fmaf(tanhf(a1[3]), xq1.w, l11);
        // z partials over this thread's k-slice 4cg..4cg+3
        float4 av0 = *(const float4*)&A[2 * rg][4 * cg];
        float4 av1 = *(const float4*)&A[2 * rg + 1][4 * cg];
        float za0=0.f, za1=0.f, zb0=0.f, zb1=0.f;   // row0: filter0 c0/c1, filter1 c0/c1
        float zc0=0.f, zc1=0.f, zd0=0.f, zd1=0.f;   // row1
#pragma unroll
        for (int j = 0; j < 4; j++) {
            int k = 4 * cg + j;
            float u0c0 = us[k * 2], u0c1 = us[k * 2 + 1];
            float u1c0 = us[128 + k * 2], u1c1 = us[128 + k * 2 + 1];
            float p0 = (&av0.x)[j], p1 = (&av1.x)[j];
            za0 = fmaf(p0, u0c0, za0); za1 = fmaf(p0, u0c1, za1);
            zb0 = fmaf(p0, u1c0, zb0); zb1 = fmaf(p0, u1c1, zb1);
            zc0 = fmaf(p1, u0c0, zc0); zc1 = fmaf(p1, u0c1, zc1);
            zd0 = fmaf(p1, u1c0, zd0); zd1 = fmaf(p1, u1c1, zd1);
        }
        // reduce 12 values over the 16 cg lanes
#pragma unroll
        for (int d = 1; d < 16; d <<= 1) {
            l00 += __shfl_xor(l00, d, 64); l01 += __shfl_xor(l01, d, 64);
            l10 += __shfl_xor(l10, d, 64); l11 += __shfl_xor(l11, d, 64);
            za0 += __shfl_xor(za0, d, 64); za1 += __shfl_xor(za1, d, 64);
            zb0 += __shfl_xor(zb0, d, 64); zb1 += __shfl_xor(zb1, d, 64);
            zc0 += __shfl_xor(zc0, d, 64); zc1 += __shfl_xor(zc1, d, 64);
            zd0 += __shfl_xor(zd0, d, 64); zd1 += __shfl_xor(zd1, d, 64);
        }
        if (cg == 0) {
            if (r0g < n) {
                float mx = fmaxf(l00, l10);
                float e0 = expf(l00 - mx), e1 = expf(l10 - mx);
                float inv = 1.0f / (e0 + e1);
                float s0 = e0 * inv, s1 = e1 * inv;
                float2 ypv = yp[r0g];
                float y0v = s0 * (za0 + vs[0]) + s1 * (zb0 + vs[2]) + ypv.x + bcs[0];
                float y1v = s0 * (za1 + vs[1]) + s1 * (zb1 + vs[3]) + ypv.y + bcs[1];
                *(float2*)&y[(size_t)r0g * 2] = make_float2(y0v, y1v);
            }
            if (r1g < n) {
                float mx = fmaxf(l01, l11);
                float e0 = expf(l01 - mx), e1 = expf(l11 - mx);
                float inv = 1.0f / (e0 + e1);
                float s0 = e0 * inv, s1 = e1 * inv;
                float2 ypv = yp[r1g];
                float y0v = s0 * (zc0 + vs[0]) + s1 * (zd0 + vs[2]) + ypv.x + bcs[0];
                float y1v = s0 * (zc1 + vs[1]) + s1 * (zd1 + vs[3]) + ypv.y + bcs[1];
                *(float2*)&y[(size_t)r1g * 2] = make_float2(y0v, y1v);
            }
        }
        __syncthreads();
    }
}

extern "C" void kernel_launch(void* const* d_in, const int* in_sizes, int n_in,
                              void* d_out, int out_size, void* d_ws, size_t ws_size,
                              hipStream_t stream)
{
    const float* x    = (const float*)d_in[0];
    const int*   ei   = (const int*)d_in[1];
    const float* w1   = (const float*)d_in[2];
    const float* b1   = (const float*)d_in[3];
    const float* w2   = (const float*)d_in[4];
    const float* b2   = (const float*)d_in[5];
    const float* w3   = (const float*)d_in[6];
    const float* b3   = (const float*)d_in[7];
    const float* wg1  = (const float*)d_in[8];
    const float* bg1  = (const float*)d_in[9];
    const float* wg2  = (const float*)d_in[10];
    const float* bg2  = (const float*)d_in[11];
    const float* beta = (const float*)d_in[12];
    const float* wf   = (const float*)d_in[13];
    const float* bf   = (const float*)d_in[14];
    const float* wx   = (const float*)d_in[15];
    const float* bx   = (const float*)d_in[16];
    const float* wc   = (const float*)d_in[17];
    const float* bc   = (const float*)d_in[18];
    float* y = (float*)d_out;

    int n = in_sizes[0] / 64;     // 100000
    int e = in_sizes[1] / 2;      // 1600000
    const int* row = ei;
    const int* col = ei + e;

    // workspace ~34MB
    char* p = (char*)d_ws;
    auto alloc = [&](size_t bytes) { char* q = p; p += (bytes + 255) & ~(size_t)255; return q; };
    float*  h    = (float*)alloc((size_t)n * 64 * 4);    // 25.6MB (h, then xp in-place)
    int*    csr  = (int*)alloc((size_t)e * 4);           // 6.4MB
    float2* nrm2 = (float2*)alloc((size_t)n * 8);        // 0.8MB
    int*    arr  = (int*)alloc((size_t)(n + 1) * 4);     // 0.4MB
    float2* yp   = (float2*)alloc((size_t)n * 8);        // 0.8MB
    int*    part = (int*)alloc(1024 * 4);                // scan block totals
    float*  pre  = (float*)alloc(8704 * 4);              // combined weights

    // agg reuses x's buffer (x dead after k_mlp; harness restores d_in).
    float* agg = (float*)d_in[0];

    int ntiles_e = (n + 31) / 32;          // 3125
    int nb = (n + 511) / 512;              // 196 scan blocks (<=256 required)

    k_pre<<<1, 256, 0, stream>>>(wg1, bg1, wg2, bg2, wf, bf, wc, pre);
    k_zero<<<(n + 256) / 256, 256, 0, stream>>>(arr, n + 1);
    k_count<<<(e + 255) / 256, 256, 0, stream>>>(col, arr, e);
    k_scan_a<<<nb, 256, 0, stream>>>(arr, part, n);
    k_scan_b<<<1, 256, 0, stream>>>(part, nb);
    k_scan_c<<<(n + 255) / 256, 256, 0, stream>>>(arr, part, n);
    k_fill<<<(e + 255) / 256, 256, 0, stream>>>(row, col, arr, csr, e);
    k_mlp<<<800, 256, 0, stream>>>(x, w1, b1, w2, b2, w3, b3, arr, h, nrm2, n);
    k_gather<<<(n + 3) / 4, 256, 0, stream>>>(h, arr, csr, nrm2, beta, wc, agg, yp, n);
    k_xp<<<800, 256, 0, stream>>>(h, wx, bx, n);
    k_epi<<<1024, 256, 0, stream>>>(agg, h, yp, pre, bc, y, n, ntiles_e);
}